// Round 1
// baseline (311.522 us; speedup 1.0000x reference)
//
#include <hip/hip_runtime.h>
#include <hip/hip_bf16.h>
#include <cstddef>
#include <cstdint>

// Problem constants
#define BB 8
#define HH 16
#define TT 128
#define SS 512
#define DD 1024
#define VV 32000
#define MM (BB * TT)   // 1024 output rows

typedef float f32x4 __attribute__((ext_vector_type(4)));
typedef short short8v __attribute__((ext_vector_type(8)));
typedef unsigned short ushort8v __attribute__((ext_vector_type(8)));

__device__ __forceinline__ unsigned short f2bf(float x) {
    __hip_bfloat16 h = __float2bfloat16(x);
    return __builtin_bit_cast(unsigned short, h);
}

__device__ __forceinline__ float wave_sum(float v) {
#pragma unroll
    for (int o = 1; o < 64; o <<= 1) v += __shfl_xor(v, o);
    return v;
}
__device__ __forceinline__ float wave_max(float v) {
#pragma unroll
    for (int o = 1; o < 64; o <<= 1) v = fmaxf(v, __shfl_xor(v, o));
    return v;
}
__device__ __forceinline__ float block_sum(float v, float* red, int tid) {
    v = wave_sum(v);
    __syncthreads();
    if ((tid & 63) == 0) red[tid >> 6] = v;
    __syncthreads();
    return red[0] + red[1] + red[2] + red[3];
}
__device__ __forceinline__ float block_max(float v, float* red, int tid) {
    v = wave_max(v);
    __syncthreads();
    if ((tid & 63) == 0) red[tid >> 6] = v;
    __syncthreads();
    return fmaxf(fmaxf(red[0], red[1]), fmaxf(red[2], red[3]));
}

// ---------------- pos_map build ----------------
__global__ void k_pm_init(int* pos_map) {
    int i = blockIdx.x * 256 + threadIdx.x;
    if (i < BB * VV) pos_map[i] = 0x7fffffff;
}

__global__ void k_pm_build(const int* __restrict__ src, int* pos_map) {
    int b = blockIdx.x, s = threadIdx.x;  // 8 x 512
    int tok = src[b * SS + s];
    atomicMin(&pos_map[b * VV + tok], s);
}

// ---------------- mw / dw dot products ----------------
// rows 0..4095: mw[b*512+s] = dot(memory[b,s,:], W_prob[0:1024])
// rows 4096..5119: dw[m] = dot(decode_output row m, W_prob[1024:2048])
__global__ __launch_bounds__(256) void k_vecdots(const float* __restrict__ memory,
                                                 const float* __restrict__ dec,
                                                 const float* __restrict__ wprob,
                                                 float* mw, float* dw) {
    int row = blockIdx.x * 4 + (threadIdx.x >> 6);
    int lane = threadIdx.x & 63;
    const float4* srcv;
    const float4* wv;
    if (row < BB * SS) {
        srcv = reinterpret_cast<const float4*>(memory + (size_t)row * DD);
        wv = reinterpret_cast<const float4*>(wprob);
    } else {
        srcv = reinterpret_cast<const float4*>(dec + (size_t)(row - BB * SS) * DD);
        wv = reinterpret_cast<const float4*>(wprob + DD);
    }
    float sum = 0.f;
#pragma unroll
    for (int k = 0; k < 4; ++k) {
        int idx = lane + 64 * k;
        float4 a = srcv[idx];
        float4 w = wv[idx];
        sum += a.x * w.x + a.y * w.y + a.z * w.z + a.w * w.w;
    }
    sum = wave_sum(sum);
    if (lane == 0) {
        if (row < BB * SS) mw[row] = sum;
        else dw[row - BB * SS] = sum;
    }
}

// ---------------- per-(b,t) row: attn mean, scatter, prob, copy-Z ----------------
__global__ __launch_bounds__(256) void k_row(const float* __restrict__ dattn,
                                             const int* __restrict__ src,
                                             const int* __restrict__ pos_map,
                                             const float* __restrict__ mw,
                                             const float* __restrict__ dw,
                                             const float* __restrict__ bprob,
                                             float* __restrict__ e_vals,
                                             float* __restrict__ prob,
                                             float* __restrict__ zc,
                                             float* __restrict__ c0) {
    int bt = blockIdx.x;
    int b = bt >> 7;
    int t = bt & 127;
    int tid = threadIdx.x;
    __shared__ float a_row[SS];
    __shared__ float vals[SS];
    __shared__ float red[4];

    // head mean
    for (int s = tid; s < SS; s += 256) {
        const float* base = dattn + ((size_t)b * HH * TT + t) * SS + s;
        float sum = 0.f;
#pragma unroll
        for (int h = 0; h < HH; ++h) sum += base[(size_t)h * TT * SS];
        a_row[s] = sum * 0.0625f;
        vals[s] = 0.f;
    }
    __syncthreads();
    // scatter to representative slots
    for (int s = tid; s < SS; s += 256) {
        int rep = pos_map[b * VV + src[b * SS + s]];
        atomicAdd(&vals[rep], a_row[s]);
    }
    __syncthreads();
    // prob gate
    float psum = 0.f;
    for (int s = tid; s < SS; s += 256) psum += a_row[s] * mw[b * SS + s];
    psum = block_sum(psum, red, tid);
    float z = psum + dw[bt] + bprob[0];
    float p = 1.0f / (1.0f + __expf(-z));
    // copy softmax stats (max over {0, rep vals})
    float mxv = -3.4e38f;
    for (int s = tid; s < SS; s += 256) {
        int rep = pos_map[b * VV + src[b * SS + s]];
        if (rep == s) mxv = fmaxf(mxv, vals[s]);
    }
    mxv = block_max(mxv, red, tid);
    float m_c = fmaxf(0.0f, mxv);
    float sexp = 0.f, cnt = 0.f;
    for (int s = tid; s < SS; s += 256) {
        int rep = pos_map[b * VV + src[b * SS + s]];
        float e = 0.0f;
        if (rep == s) {
            e = __expf(vals[s] - m_c);
            sexp += e;
            cnt += 1.0f;
        }
        e_vals[(size_t)bt * SS + s] = e;
    }
    sexp = block_sum(sexp, red, tid);
    cnt = block_sum(cnt, red, tid);
    if (tid == 0) {
        prob[bt] = p;
        zc[bt] = ((float)VV - cnt) * __expf(-m_c) + sexp;
        c0[bt] = __expf(-m_c);
    }
}

// ---------------- bf16 MFMA GEMM: gen_logits = dec @ W_gen^T + b_gen ----------------
#define GBM 128
#define GBN 128
#define GBK 32
#define LDK 40  // padded LDS row (elements); 80B stride, keeps 16B alignment

__global__ __launch_bounds__(256) void k_gemm(const float* __restrict__ A,
                                              const float* __restrict__ Wg,
                                              const float* __restrict__ bgen,
                                              float* __restrict__ out) {
    __shared__ unsigned short As[GBM * LDK];
    __shared__ unsigned short Bs[GBN * LDK];
    int tid = threadIdx.x;
    int bid = blockIdx.x;
    int mt = bid & 7;    // 8 M-tiles (fastest: neighbors share the B-tile)
    int nt = bid >> 3;   // 250 N-tiles
    int m0 = mt * GBM, v0 = nt * GBN;
    int lane = tid & 63, wid = tid >> 6;
    int wr = (wid >> 1) * 64, wc = (wid & 1) * 64;
    int lr = lane & 15, lk = (lane >> 4) << 3;
    int r = tid >> 1, c0 = (tid & 1) << 4;

    f32x4 acc[4][4] = {};

    for (int k0 = 0; k0 < DD; k0 += GBK) {
        // stage A-tile and B-tile (f32 -> bf16 in registers)
        {
            const float4* pa = reinterpret_cast<const float4*>(A + (size_t)(m0 + r) * DD + k0 + c0);
            float4 x0 = pa[0], x1 = pa[1], x2 = pa[2], x3 = pa[3];
            ushort8v u0, u1;
            u0[0] = f2bf(x0.x); u0[1] = f2bf(x0.y); u0[2] = f2bf(x0.z); u0[3] = f2bf(x0.w);
            u0[4] = f2bf(x1.x); u0[5] = f2bf(x1.y); u0[6] = f2bf(x1.z); u0[7] = f2bf(x1.w);
            u1[0] = f2bf(x2.x); u1[1] = f2bf(x2.y); u1[2] = f2bf(x2.z); u1[3] = f2bf(x2.w);
            u1[4] = f2bf(x3.x); u1[5] = f2bf(x3.y); u1[6] = f2bf(x3.z); u1[7] = f2bf(x3.w);
            *reinterpret_cast<ushort8v*>(&As[r * LDK + c0]) = u0;
            *reinterpret_cast<ushort8v*>(&As[r * LDK + c0 + 8]) = u1;

            const float4* pb = reinterpret_cast<const float4*>(Wg + (size_t)(v0 + r) * DD + k0 + c0);
            float4 y0 = pb[0], y1 = pb[1], y2 = pb[2], y3 = pb[3];
            ushort8v v0u, v1u;
            v0u[0] = f2bf(y0.x); v0u[1] = f2bf(y0.y); v0u[2] = f2bf(y0.z); v0u[3] = f2bf(y0.w);
            v0u[4] = f2bf(y1.x); v0u[5] = f2bf(y1.y); v0u[6] = f2bf(y1.z); v0u[7] = f2bf(y1.w);
            v1u[0] = f2bf(y2.x); v1u[1] = f2bf(y2.y); v1u[2] = f2bf(y2.z); v1u[3] = f2bf(y2.w);
            v1u[4] = f2bf(y3.x); v1u[5] = f2bf(y3.y); v1u[6] = f2bf(y3.z); v1u[7] = f2bf(y3.w);
            *reinterpret_cast<ushort8v*>(&Bs[r * LDK + c0]) = v0u;
            *reinterpret_cast<ushort8v*>(&Bs[r * LDK + c0 + 8]) = v1u;
        }
        __syncthreads();

        short8v af[4], bf[4];
#pragma unroll
        for (int i = 0; i < 4; ++i)
            af[i] = *reinterpret_cast<const short8v*>(&As[(wr + i * 16 + lr) * LDK + lk]);
#pragma unroll
        for (int j = 0; j < 4; ++j)
            bf[j] = *reinterpret_cast<const short8v*>(&Bs[(wc + j * 16 + lr) * LDK + lk]);
#pragma unroll
        for (int i = 0; i < 4; ++i)
#pragma unroll
            for (int j = 0; j < 4; ++j)
                acc[i][j] = __builtin_amdgcn_mfma_f32_16x16x32_bf16(af[i], bf[j], acc[i][j], 0, 0, 0);
        __syncthreads();
    }

    // epilogue: C/D layout col = lane&15, row = (lane>>4)*4 + reg
    int rowf = (lane >> 4) << 2;
#pragma unroll
    for (int i = 0; i < 4; ++i) {
#pragma unroll
        for (int j = 0; j < 4; ++j) {
            int c = wc + j * 16 + (lane & 15);
            int gv = v0 + c;
            float bgj = bgen[gv];
#pragma unroll
            for (int rr = 0; rr < 4; ++rr) {
                int gm = m0 + wr + i * 16 + rowf + rr;
                out[(size_t)gm * VV + gv] = acc[i][j][rr] + bgj;
            }
        }
    }
}

// ---------------- per-row max + sumexp over gen logits ----------------
__global__ __launch_bounds__(256) void k_rowred(const float* __restrict__ gen,
                                                float* gmax, float* zg) {
    int m = blockIdx.x;
    int tid = threadIdx.x;
    const float4* row = reinterpret_cast<const float4*>(gen + (size_t)m * VV);
    __shared__ float red[4];
    float mx = -3.4e38f;
    for (int i = tid; i < VV / 4; i += 256) {
        float4 x = row[i];
        mx = fmaxf(mx, fmaxf(fmaxf(x.x, x.y), fmaxf(x.z, x.w)));
    }
    mx = block_max(mx, red, tid);
    float se = 0.f;
    for (int i = tid; i < VV / 4; i += 256) {
        float4 x = row[i];
        se += __expf(x.x - mx) + __expf(x.y - mx) + __expf(x.z - mx) + __expf(x.w - mx);
    }
    se = block_sum(se, red, tid);
    if (tid == 0) {
        gmax[m] = mx;
        zg[m] = se;
    }
}

// ---------------- final combine, in place over d_out ----------------
__global__ __launch_bounds__(256) void k_final(float* __restrict__ gen,
                                               const int* __restrict__ pos_map,
                                               const float* __restrict__ e_vals,
                                               const float* __restrict__ prob,
                                               const float* __restrict__ zc,
                                               const float* __restrict__ c0,
                                               const float* __restrict__ gmax,
                                               const float* __restrict__ zg) {
    int m = blockIdx.x;
    int b = m >> 7;
    int tid = threadIdx.x;
    float p = prob[m];
    float A1 = p / zg[m];
    float A2 = (1.0f - p) / zc[m];
    float gm = gmax[m];
    float cc = c0[m];
    const float* ev = e_vals + (size_t)m * SS;
    float4* row = reinterpret_cast<float4*>(gen + (size_t)m * VV);
    const int4* pm = reinterpret_cast<const int4*>(pos_map + b * VV);
    for (int i = tid; i < VV / 4; i += 256) {
        float4 g = row[i];
        int4 rp = pm[i];
        float4 o;
        o.x = __logf(A1 * __expf(g.x - gm) + A2 * ((rp.x < SS) ? ev[rp.x] : cc));
        o.y = __logf(A1 * __expf(g.y - gm) + A2 * ((rp.y < SS) ? ev[rp.y] : cc));
        o.z = __logf(A1 * __expf(g.z - gm) + A2 * ((rp.z < SS) ? ev[rp.z] : cc));
        o.w = __logf(A1 * __expf(g.w - gm) + A2 * ((rp.w < SS) ? ev[rp.w] : cc));
        row[i] = o;
    }
}

extern "C" void kernel_launch(void* const* d_in, const int* in_sizes, int n_in,
                              void* d_out, int out_size, void* d_ws, size_t ws_size,
                              hipStream_t stream) {
    const int* src = (const int*)d_in[0];
    const float* dec = (const float*)d_in[1];
    const float* dattn = (const float*)d_in[2];
    const float* mem = (const float*)d_in[3];
    const float* wgen = (const float*)d_in[4];
    const float* bgen = (const float*)d_in[5];
    const float* wprob = (const float*)d_in[6];
    const float* bprob = (const float*)d_in[7];
    float* out = (float*)d_out;
    char* ws = (char*)d_ws;

    int* pos_map = (int*)(ws + 0);                 // 8*32000*4 = 1,024,000 B
    float* e_vals = (float*)(ws + 1048576);        // 1024*512*4 = 2 MB
    float* mw = (float*)(ws + 3145728);            // 16 KB
    float* dw = (float*)(ws + 3145728 + 16384);    // 4 KB
    float* prob = (float*)(ws + 3145728 + 20480);
    float* zc = (float*)(ws + 3145728 + 24576);
    float* c0 = (float*)(ws + 3145728 + 28672);
    float* gmax = (float*)(ws + 3145728 + 32768);
    float* zg = (float*)(ws + 3145728 + 36864);

    k_pm_init<<<(BB * VV + 255) / 256, 256, 0, stream>>>(pos_map);
    k_pm_build<<<BB, SS, 0, stream>>>(src, pos_map);
    k_vecdots<<<(BB * SS + MM) / 4, 256, 0, stream>>>(mem, dec, wprob, mw, dw);
    k_row<<<MM, 256, 0, stream>>>(dattn, src, pos_map, mw, dw, bprob, e_vals, prob, zc, c0);
    k_gemm<<<(MM / GBM) * (VV / GBN), 256, 0, stream>>>(dec, wgen, bgen, out);
    k_rowred<<<MM, 256, 0, stream>>>(out, gmax, zg);
    k_final<<<MM, 256, 0, stream>>>(out, pos_map, e_vals, prob, zc, c0, gmax, zg);
}

// Round 2
// 256.485 us; speedup vs baseline: 1.2146x; 1.2146x over previous
//
#include <hip/hip_runtime.h>
#include <hip/hip_bf16.h>
#include <cstddef>
#include <cstdint>

// Problem constants
#define BB 8
#define HH 16
#define TT 128
#define SS 512
#define DD 1024
#define VV 32000
#define MM (BB * TT)   // 1024 output rows

typedef float f32x4 __attribute__((ext_vector_type(4)));
typedef short short8v __attribute__((ext_vector_type(8)));
typedef unsigned short ushort8v __attribute__((ext_vector_type(8)));

__device__ __forceinline__ unsigned short f2bf(float x) {
    __hip_bfloat16 h = __float2bfloat16(x);
    return __builtin_bit_cast(unsigned short, h);
}

__device__ __forceinline__ float wave_sum(float v) {
#pragma unroll
    for (int o = 1; o < 64; o <<= 1) v += __shfl_xor(v, o);
    return v;
}
__device__ __forceinline__ float wave_max(float v) {
#pragma unroll
    for (int o = 1; o < 64; o <<= 1) v = fmaxf(v, __shfl_xor(v, o));
    return v;
}
__device__ __forceinline__ float block_sum(float v, float* red, int tid) {
    v = wave_sum(v);
    __syncthreads();
    if ((tid & 63) == 0) red[tid >> 6] = v;
    __syncthreads();
    return red[0] + red[1] + red[2] + red[3];
}
__device__ __forceinline__ float block_max(float v, float* red, int tid) {
    v = wave_max(v);
    __syncthreads();
    if ((tid & 63) == 0) red[tid >> 6] = v;
    __syncthreads();
    return fmaxf(fmaxf(red[0], red[1]), fmaxf(red[2], red[3]));
}

// ---------------- pos_map build + zg zero ----------------
__global__ void k_pm_init(int* pos_map, float* zg) {
    int i = blockIdx.x * 256 + threadIdx.x;
    if (i < BB * VV) pos_map[i] = 0x7fffffff;
    if (i < MM) zg[i] = 0.0f;
}

__global__ void k_pm_build(const int* __restrict__ src, int* pos_map) {
    int b = blockIdx.x, s = threadIdx.x;  // 8 x 512
    int tok = src[b * SS + s];
    atomicMin(&pos_map[b * VV + tok], s);
}

// ---------------- f32 -> bf16 cast (8 elems/thread, grid-stride) ----------------
__global__ __launch_bounds__(256) void k_cast(const float* __restrict__ in,
                                              unsigned short* __restrict__ outp, int n8) {
    int stride = gridDim.x * 256;
    for (int i = blockIdx.x * 256 + threadIdx.x; i < n8; i += stride) {
        const float4* p = reinterpret_cast<const float4*>(in + (size_t)i * 8);
        float4 a = p[0], b = p[1];
        ushort8v u;
        u[0] = f2bf(a.x); u[1] = f2bf(a.y); u[2] = f2bf(a.z); u[3] = f2bf(a.w);
        u[4] = f2bf(b.x); u[5] = f2bf(b.y); u[6] = f2bf(b.z); u[7] = f2bf(b.w);
        *reinterpret_cast<ushort8v*>(outp + (size_t)i * 8) = u;
    }
}

// ---------------- mw / dw dot products ----------------
__global__ __launch_bounds__(256) void k_vecdots(const float* __restrict__ memory,
                                                 const float* __restrict__ dec,
                                                 const float* __restrict__ wprob,
                                                 float* mw, float* dw) {
    int row = blockIdx.x * 4 + (threadIdx.x >> 6);
    int lane = threadIdx.x & 63;
    const float4* srcv;
    const float4* wv;
    if (row < BB * SS) {
        srcv = reinterpret_cast<const float4*>(memory + (size_t)row * DD);
        wv = reinterpret_cast<const float4*>(wprob);
    } else {
        srcv = reinterpret_cast<const float4*>(dec + (size_t)(row - BB * SS) * DD);
        wv = reinterpret_cast<const float4*>(wprob + DD);
    }
    float sum = 0.f;
#pragma unroll
    for (int k = 0; k < 4; ++k) {
        int idx = lane + 64 * k;
        float4 a = srcv[idx];
        float4 w = wv[idx];
        sum += a.x * w.x + a.y * w.y + a.z * w.z + a.w * w.w;
    }
    sum = wave_sum(sum);
    if (lane == 0) {
        if (row < BB * SS) mw[row] = sum;
        else dw[row - BB * SS] = sum;
    }
}

// ---------------- per-(b,t) row: attn mean, scatter, prob, copy-Z ----------------
__global__ __launch_bounds__(256) void k_row(const float* __restrict__ dattn,
                                             const int* __restrict__ src,
                                             const int* __restrict__ pos_map,
                                             const float* __restrict__ mw,
                                             const float* __restrict__ dw,
                                             const float* __restrict__ bprob,
                                             float* __restrict__ e_vals,
                                             float* __restrict__ prob,
                                             float* __restrict__ zc,
                                             float* __restrict__ c0) {
    int bt = blockIdx.x;
    int b = bt >> 7;
    int t = bt & 127;
    int tid = threadIdx.x;
    __shared__ float a_row[SS];
    __shared__ float vals[SS];
    __shared__ float red[4];

    for (int s = tid; s < SS; s += 256) {
        const float* base = dattn + ((size_t)b * HH * TT + t) * SS + s;
        float sum = 0.f;
#pragma unroll
        for (int h = 0; h < HH; ++h) sum += base[(size_t)h * TT * SS];
        a_row[s] = sum * 0.0625f;
        vals[s] = 0.f;
    }
    __syncthreads();
    for (int s = tid; s < SS; s += 256) {
        int rep = pos_map[b * VV + src[b * SS + s]];
        atomicAdd(&vals[rep], a_row[s]);
    }
    __syncthreads();
    float psum = 0.f;
    for (int s = tid; s < SS; s += 256) psum += a_row[s] * mw[b * SS + s];
    psum = block_sum(psum, red, tid);
    float z = psum + dw[bt] + bprob[0];
    float p = 1.0f / (1.0f + __expf(-z));
    float mxv = -3.4e38f;
    for (int s = tid; s < SS; s += 256) {
        int rep = pos_map[b * VV + src[b * SS + s]];
        if (rep == s) mxv = fmaxf(mxv, vals[s]);
    }
    mxv = block_max(mxv, red, tid);
    float m_c = fmaxf(0.0f, mxv);
    float sexp = 0.f, cnt = 0.f;
    for (int s = tid; s < SS; s += 256) {
        int rep = pos_map[b * VV + src[b * SS + s]];
        float e = 0.0f;
        if (rep == s) {
            e = __expf(vals[s] - m_c);
            sexp += e;
            cnt += 1.0f;
        }
        e_vals[(size_t)bt * SS + s] = e;
    }
    sexp = block_sum(sexp, red, tid);
    cnt = block_sum(cnt, red, tid);
    if (tid == 0) {
        prob[bt] = p;
        zc[bt] = ((float)VV - cnt) * __expf(-m_c) + sexp;
        c0[bt] = __expf(-m_c);
    }
}

// ---------------- epilogue helper: store + per-row exp-sum atomics ----------------
__device__ __forceinline__ void gemm_epilogue(f32x4 acc[4][4], const float* bgen,
                                              float* out, float* zg,
                                              int m0, int v0, int wr, int wc, int lane) {
    int colb = lane & 15;
    int rgrp = lane >> 4;
#pragma unroll
    for (int i = 0; i < 4; ++i) {
        float es0 = 0.f, es1 = 0.f, es2 = 0.f, es3 = 0.f;
#pragma unroll
        for (int j = 0; j < 4; ++j) {
            int gv = v0 + wc + j * 16 + colb;
            float bgj = bgen[gv];
            int gmb = m0 + wr + i * 16 + rgrp * 4;
            float v0f = acc[i][j][0] + bgj;
            float v1f = acc[i][j][1] + bgj;
            float v2f = acc[i][j][2] + bgj;
            float v3f = acc[i][j][3] + bgj;
            out[(size_t)(gmb + 0) * VV + gv] = v0f;
            out[(size_t)(gmb + 1) * VV + gv] = v1f;
            out[(size_t)(gmb + 2) * VV + gv] = v2f;
            out[(size_t)(gmb + 3) * VV + gv] = v3f;
            es0 += __expf(v0f); es1 += __expf(v1f);
            es2 += __expf(v2f); es3 += __expf(v3f);
        }
        float es[4] = {es0, es1, es2, es3};
#pragma unroll
        for (int rr = 0; rr < 4; ++rr) {
            float e = es[rr];
            e += __shfl_xor(e, 1); e += __shfl_xor(e, 2);
            e += __shfl_xor(e, 4); e += __shfl_xor(e, 8);
            if (colb == 0) atomicAdd(&zg[m0 + wr + i * 16 + rgrp * 4 + rr], e);
        }
    }
}

// ---------------- fast GEMM: bf16 inputs, global_load_lds staging ----------------
#define Bb 128
#define Bn 128
#define Bk 64

__global__ __launch_bounds__(256) void k_gemm_bf(const unsigned short* __restrict__ Abf,
                                                 const unsigned short* __restrict__ Wbf,
                                                 const float* __restrict__ bgen,
                                                 float* __restrict__ out,
                                                 float* __restrict__ zg) {
    __shared__ unsigned short As[Bb * Bk];
    __shared__ unsigned short Bs[Bn * Bk];
    int tid = threadIdx.x;
    int p = blockIdx.x;
    // XCD-bijective swizzle: 2000 blocks = 8 XCDs x 250; keep all 8 M-tiles of
    // one B-tile on the same XCD so W_gen is fetched once per L2.
    int l = (p & 7) * 250 + (p >> 3);
    int mt = l & 7, nt = l >> 3;
    int m0 = mt * Bb, v0 = nt * Bn;
    int lane = tid & 63, wid = tid >> 6;
    int wr = (wid >> 1) * 64, wc = (wid & 1) * 64;
    int lr = lane & 15, lk = (lane >> 4) << 3;

    // staging: each wave owns 32 rows of A and 32 rows of B per K-tile,
    // 4 issues x (8 rows x 64 cols) each; linear LDS, lane i -> base + i*16B.
    int srow = lane >> 3;
    int scol = (lane & 7) << 3;
    const unsigned short* ga = Abf + (size_t)(m0 + wid * 32 + srow) * DD + scol;
    const unsigned short* gb = Wbf + (size_t)(v0 + wid * 32 + srow) * DD + scol;
    unsigned short* lva = As + wid * 32 * Bk;
    unsigned short* lvb = Bs + wid * 32 * Bk;

    f32x4 acc[4][4] = {};

    for (int k0 = 0; k0 < DD; k0 += Bk) {
#pragma unroll
        for (int q = 0; q < 4; ++q) {
            __builtin_amdgcn_global_load_lds(
                (const __attribute__((address_space(1))) void*)(ga + (size_t)(q * 8) * DD + k0),
                (__attribute__((address_space(3))) void*)(lva + q * 8 * Bk), 16, 0, 0);
            __builtin_amdgcn_global_load_lds(
                (const __attribute__((address_space(1))) void*)(gb + (size_t)(q * 8) * DD + k0),
                (__attribute__((address_space(3))) void*)(lvb + q * 8 * Bk), 16, 0, 0);
        }
        __syncthreads();
#pragma unroll
        for (int ks = 0; ks < 2; ++ks) {
            short8v af[4], bfr[4];
#pragma unroll
            for (int i = 0; i < 4; ++i)
                af[i] = *reinterpret_cast<const short8v*>(&As[(wr + i * 16 + lr) * Bk + ks * 32 + lk]);
#pragma unroll
            for (int j = 0; j < 4; ++j)
                bfr[j] = *reinterpret_cast<const short8v*>(&Bs[(wc + j * 16 + lr) * Bk + ks * 32 + lk]);
#pragma unroll
            for (int i = 0; i < 4; ++i)
#pragma unroll
                for (int j = 0; j < 4; ++j)
                    acc[i][j] = __builtin_amdgcn_mfma_f32_16x16x32_bf16(af[i], bfr[j], acc[i][j], 0, 0, 0);
        }
        __syncthreads();
    }
    gemm_epilogue(acc, bgen, out, zg, m0, v0, wr, wc, lane);
}

// ---------------- fallback GEMM (f32 inputs, in-register cast) ----------------
#define LDK 40

__global__ __launch_bounds__(256) void k_gemm_f32(const float* __restrict__ A,
                                                  const float* __restrict__ Wg,
                                                  const float* __restrict__ bgen,
                                                  float* __restrict__ out,
                                                  float* __restrict__ zg) {
    __shared__ unsigned short As[Bb * LDK];
    __shared__ unsigned short Bs[Bn * LDK];
    int tid = threadIdx.x;
    int bid = blockIdx.x;
    int mt = bid & 7;
    int nt = bid >> 3;
    int m0 = mt * Bb, v0 = nt * Bn;
    int lane = tid & 63, wid = tid >> 6;
    int wr = (wid >> 1) * 64, wc = (wid & 1) * 64;
    int lr = lane & 15, lk = (lane >> 4) << 3;
    int r = tid >> 1, c0 = (tid & 1) << 4;

    f32x4 acc[4][4] = {};

    for (int k0 = 0; k0 < DD; k0 += 32) {
        {
            const float4* pa = reinterpret_cast<const float4*>(A + (size_t)(m0 + r) * DD + k0 + c0);
            float4 x0 = pa[0], x1 = pa[1], x2 = pa[2], x3 = pa[3];
            ushort8v u0, u1;
            u0[0] = f2bf(x0.x); u0[1] = f2bf(x0.y); u0[2] = f2bf(x0.z); u0[3] = f2bf(x0.w);
            u0[4] = f2bf(x1.x); u0[5] = f2bf(x1.y); u0[6] = f2bf(x1.z); u0[7] = f2bf(x1.w);
            u1[0] = f2bf(x2.x); u1[1] = f2bf(x2.y); u1[2] = f2bf(x2.z); u1[3] = f2bf(x2.w);
            u1[4] = f2bf(x3.x); u1[5] = f2bf(x3.y); u1[6] = f2bf(x3.z); u1[7] = f2bf(x3.w);
            *reinterpret_cast<ushort8v*>(&As[r * LDK + c0]) = u0;
            *reinterpret_cast<ushort8v*>(&As[r * LDK + c0 + 8]) = u1;

            const float4* pb = reinterpret_cast<const float4*>(Wg + (size_t)(v0 + r) * DD + k0 + c0);
            float4 y0 = pb[0], y1 = pb[1], y2 = pb[2], y3 = pb[3];
            ushort8v w0, w1;
            w0[0] = f2bf(y0.x); w0[1] = f2bf(y0.y); w0[2] = f2bf(y0.z); w0[3] = f2bf(y0.w);
            w0[4] = f2bf(y1.x); w0[5] = f2bf(y1.y); w0[6] = f2bf(y1.z); w0[7] = f2bf(y1.w);
            w1[0] = f2bf(y2.x); w1[1] = f2bf(y2.y); w1[2] = f2bf(y2.z); w1[3] = f2bf(y2.w);
            w1[4] = f2bf(y3.x); w1[5] = f2bf(y3.y); w1[6] = f2bf(y3.z); w1[7] = f2bf(y3.w);
            *reinterpret_cast<ushort8v*>(&Bs[r * LDK + c0]) = w0;
            *reinterpret_cast<ushort8v*>(&Bs[r * LDK + c0 + 8]) = w1;
        }
        __syncthreads();

        short8v af[4], bfr[4];
#pragma unroll
        for (int i = 0; i < 4; ++i)
            af[i] = *reinterpret_cast<const short8v*>(&As[(wr + i * 16 + lr) * LDK + lk]);
#pragma unroll
        for (int j = 0; j < 4; ++j)
            bfr[j] = *reinterpret_cast<const short8v*>(&Bs[(wc + j * 16 + lr) * LDK + lk]);
#pragma unroll
        for (int i = 0; i < 4; ++i)
#pragma unroll
            for (int j = 0; j < 4; ++j)
                acc[i][j] = __builtin_amdgcn_mfma_f32_16x16x32_bf16(af[i], bfr[j], acc[i][j], 0, 0, 0);
        __syncthreads();
    }
    gemm_epilogue(acc, bgen, out, zg, m0, v0, wr, wc, lane);
}

// ---------------- final combine, in place over d_out (gm = 0) ----------------
__global__ __launch_bounds__(256) void k_final(float* __restrict__ gen,
                                               const int* __restrict__ pos_map,
                                               const float* __restrict__ e_vals,
                                               const float* __restrict__ prob,
                                               const float* __restrict__ zc,
                                               const float* __restrict__ c0,
                                               const float* __restrict__ zg) {
    int m = blockIdx.x;
    int b = m >> 7;
    int tid = threadIdx.x;
    float p = prob[m];
    float A1 = p / zg[m];
    float A2 = (1.0f - p) / zc[m];
    float cc = c0[m];
    const float* ev = e_vals + (size_t)m * SS;
    float4* row = reinterpret_cast<float4*>(gen + (size_t)m * VV);
    const int4* pm = reinterpret_cast<const int4*>(pos_map + b * VV);
    for (int i = tid; i < VV / 4; i += 256) {
        float4 g = row[i];
        int4 rp = pm[i];
        float4 o;
        o.x = __logf(A1 * __expf(g.x) + A2 * ((rp.x < SS) ? ev[rp.x] : cc));
        o.y = __logf(A1 * __expf(g.y) + A2 * ((rp.y < SS) ? ev[rp.y] : cc));
        o.z = __logf(A1 * __expf(g.z) + A2 * ((rp.z < SS) ? ev[rp.z] : cc));
        o.w = __logf(A1 * __expf(g.w) + A2 * ((rp.w < SS) ? ev[rp.w] : cc));
        row[i] = o;
    }
}

extern "C" void kernel_launch(void* const* d_in, const int* in_sizes, int n_in,
                              void* d_out, int out_size, void* d_ws, size_t ws_size,
                              hipStream_t stream) {
    const int* src = (const int*)d_in[0];
    const float* dec = (const float*)d_in[1];
    const float* dattn = (const float*)d_in[2];
    const float* mem = (const float*)d_in[3];
    const float* wgen = (const float*)d_in[4];
    const float* bgen = (const float*)d_in[5];
    const float* wprob = (const float*)d_in[6];
    const float* bprob = (const float*)d_in[7];
    float* out = (float*)d_out;
    char* ws = (char*)d_ws;

    // ws layout
    int* pos_map = (int*)(ws + 0);                       // 1,024,000 B (pad 1 MB)
    float* e_vals = (float*)(ws + 1048576);              // 2 MB
    float* mw   = (float*)(ws + 3145728);                // 16 KB
    float* dw   = (float*)(ws + 3145728 + 16384);
    float* prob = (float*)(ws + 3145728 + 20480);
    float* zc   = (float*)(ws + 3145728 + 24576);
    float* c0   = (float*)(ws + 3145728 + 28672);
    float* zg   = (float*)(ws + 3145728 + 32768);
    unsigned short* Wbf = (unsigned short*)(ws + 3211264);              // 65,536,000 B
    unsigned short* Abf = (unsigned short*)(ws + 3211264 + 65536000);   // 2 MB
    const size_t NEEDED = 3211264ull + 65536000ull + 2097152ull;

    k_pm_init<<<(BB * VV + 255) / 256, 256, 0, stream>>>(pos_map, zg);
    k_pm_build<<<BB, SS, 0, stream>>>(src, pos_map);
    k_vecdots<<<(BB * SS + MM) / 4, 256, 0, stream>>>(mem, dec, wprob, mw, dw);
    k_row<<<MM, 256, 0, stream>>>(dattn, src, pos_map, mw, dw, bprob, e_vals, prob, zc, c0);

    if (ws_size >= NEEDED) {
        k_cast<<<2048, 256, 0, stream>>>(wgen, Wbf, VV * DD / 8);
        k_cast<<<512, 256, 0, stream>>>(dec, Abf, MM * DD / 8);
        k_gemm_bf<<<(MM / Bb) * (VV / Bn), 256, 0, stream>>>(Abf, Wbf, bgen, out, zg);
    } else {
        k_gemm_f32<<<(MM / Bb) * (VV / Bn), 256, 0, stream>>>(dec, wgen, bgen, out, zg);
    }
    k_final<<<MM, 256, 0, stream>>>(out, pos_map, e_vals, prob, zc, c0, zg);
}

// Round 3
// 249.727 us; speedup vs baseline: 1.2475x; 1.0271x over previous
//
#include <hip/hip_runtime.h>
#include <hip/hip_bf16.h>
#include <cstddef>
#include <cstdint>

// Problem constants
#define BB 8
#define HH 16
#define TT 128
#define SS 512
#define DD 1024
#define VV 32000
#define MM (BB * TT)   // 1024 output rows

typedef float f32x4 __attribute__((ext_vector_type(4)));
typedef short short8v __attribute__((ext_vector_type(8)));
typedef unsigned short ushort8v __attribute__((ext_vector_type(8)));

__device__ __forceinline__ unsigned short f2bf(float x) {
    __hip_bfloat16 h = __float2bfloat16(x);
    return __builtin_bit_cast(unsigned short, h);
}

__device__ __forceinline__ float wave_sum(float v) {
#pragma unroll
    for (int o = 1; o < 64; o <<= 1) v += __shfl_xor(v, o);
    return v;
}
__device__ __forceinline__ float wave_max(float v) {
#pragma unroll
    for (int o = 1; o < 64; o <<= 1) v = fmaxf(v, __shfl_xor(v, o));
    return v;
}
__device__ __forceinline__ float block_sum(float v, float* red, int tid) {
    v = wave_sum(v);
    __syncthreads();
    if ((tid & 63) == 0) red[tid >> 6] = v;
    __syncthreads();
    return red[0] + red[1] + red[2] + red[3];
}
__device__ __forceinline__ float block_max(float v, float* red, int tid) {
    v = wave_max(v);
    __syncthreads();
    if ((tid & 63) == 0) red[tid >> 6] = v;
    __syncthreads();
    return fmaxf(fmaxf(red[0], red[1]), fmaxf(red[2], red[3]));
}

// ---------------- pos_map build + zg zero ----------------
__global__ void k_pm_init(int* pos_map, float* zg) {
    int i = blockIdx.x * 256 + threadIdx.x;
    if (i < BB * VV) pos_map[i] = 0x7fffffff;
    if (i < MM) zg[i] = 0.0f;
}

__global__ void k_pm_build(const int* __restrict__ src, int* pos_map) {
    int b = blockIdx.x, s = threadIdx.x;  // 8 x 512
    int tok = src[b * SS + s];
    atomicMin(&pos_map[b * VV + tok], s);
}

// ---------------- f32 -> bf16 cast (8 elems/thread, grid-stride) ----------------
__global__ __launch_bounds__(256) void k_cast(const float* __restrict__ in,
                                              unsigned short* __restrict__ outp, int n8) {
    int stride = gridDim.x * 256;
    for (int i = blockIdx.x * 256 + threadIdx.x; i < n8; i += stride) {
        const float4* p = reinterpret_cast<const float4*>(in + (size_t)i * 8);
        float4 a = p[0], b = p[1];
        ushort8v u;
        u[0] = f2bf(a.x); u[1] = f2bf(a.y); u[2] = f2bf(a.z); u[3] = f2bf(a.w);
        u[4] = f2bf(b.x); u[5] = f2bf(b.y); u[6] = f2bf(b.z); u[7] = f2bf(b.w);
        *reinterpret_cast<ushort8v*>(outp + (size_t)i * 8) = u;
    }
}

// ---------------- mw / dw dot products ----------------
__global__ __launch_bounds__(256) void k_vecdots(const float* __restrict__ memory,
                                                 const float* __restrict__ dec,
                                                 const float* __restrict__ wprob,
                                                 float* mw, float* dw) {
    int row = blockIdx.x * 4 + (threadIdx.x >> 6);
    int lane = threadIdx.x & 63;
    const float4* srcv;
    const float4* wv;
    if (row < BB * SS) {
        srcv = reinterpret_cast<const float4*>(memory + (size_t)row * DD);
        wv = reinterpret_cast<const float4*>(wprob);
    } else {
        srcv = reinterpret_cast<const float4*>(dec + (size_t)(row - BB * SS) * DD);
        wv = reinterpret_cast<const float4*>(wprob + DD);
    }
    float sum = 0.f;
#pragma unroll
    for (int k = 0; k < 4; ++k) {
        int idx = lane + 64 * k;
        float4 a = srcv[idx];
        float4 w = wv[idx];
        sum += a.x * w.x + a.y * w.y + a.z * w.z + a.w * w.w;
    }
    sum = wave_sum(sum);
    if (lane == 0) {
        if (row < BB * SS) mw[row] = sum;
        else dw[row - BB * SS] = sum;
    }
}

// ---------------- per-(b,t) row: attn mean, scatter, prob, copy-Z ----------------
__global__ __launch_bounds__(256) void k_row(const float* __restrict__ dattn,
                                             const int* __restrict__ src,
                                             const int* __restrict__ pos_map,
                                             const float* __restrict__ mw,
                                             const float* __restrict__ dw,
                                             const float* __restrict__ bprob,
                                             float* __restrict__ e_vals,
                                             float* __restrict__ prob,
                                             float* __restrict__ zc,
                                             float* __restrict__ c0) {
    int bt = blockIdx.x;
    int b = bt >> 7;
    int t = bt & 127;
    int tid = threadIdx.x;
    __shared__ float a_row[SS];
    __shared__ float vals[SS];
    __shared__ float red[4];

    for (int s = tid; s < SS; s += 256) {
        const float* base = dattn + ((size_t)b * HH * TT + t) * SS + s;
        float sum = 0.f;
#pragma unroll
        for (int h = 0; h < HH; ++h) sum += base[(size_t)h * TT * SS];
        a_row[s] = sum * 0.0625f;
        vals[s] = 0.f;
    }
    __syncthreads();
    for (int s = tid; s < SS; s += 256) {
        int rep = pos_map[b * VV + src[b * SS + s]];
        atomicAdd(&vals[rep], a_row[s]);
    }
    __syncthreads();
    float psum = 0.f;
    for (int s = tid; s < SS; s += 256) psum += a_row[s] * mw[b * SS + s];
    psum = block_sum(psum, red, tid);
    float z = psum + dw[bt] + bprob[0];
    float p = 1.0f / (1.0f + __expf(-z));
    float mxv = -3.4e38f;
    for (int s = tid; s < SS; s += 256) {
        int rep = pos_map[b * VV + src[b * SS + s]];
        if (rep == s) mxv = fmaxf(mxv, vals[s]);
    }
    mxv = block_max(mxv, red, tid);
    float m_c = fmaxf(0.0f, mxv);
    float sexp = 0.f, cnt = 0.f;
    for (int s = tid; s < SS; s += 256) {
        int rep = pos_map[b * VV + src[b * SS + s]];
        float e = 0.0f;
        if (rep == s) {
            e = __expf(vals[s] - m_c);
            sexp += e;
            cnt += 1.0f;
        }
        e_vals[(size_t)bt * SS + s] = e;
    }
    sexp = block_sum(sexp, red, tid);
    cnt = block_sum(cnt, red, tid);
    if (tid == 0) {
        prob[bt] = p;
        zc[bt] = ((float)VV - cnt) * __expf(-m_c) + sexp;
        c0[bt] = __expf(-m_c);
    }
}

// =====================================================================
// 256x256 bf16 MFMA GEMM, 8 waves, BK=64, dbuf LDS, counted vmcnt (T2-T5)
// =====================================================================
#define Bk 64
#define NKT 16   // K tiles = 1024/64

__global__ __launch_bounds__(512, 2) void k_gemm_bf(const unsigned short* __restrict__ Abf,
                                                    const unsigned short* __restrict__ Wbf,
                                                    const float* __restrict__ bgen,
                                                    float* __restrict__ out,
                                                    float* __restrict__ zg) {
    // 128 KiB LDS: [As0 32K][Bs0 32K][As1 32K][Bs1 32K] (ushort elements)
    __shared__ unsigned short lds[65536];

    int tid = threadIdx.x;
    int p = blockIdx.x;
    // m204 bijective XCD swizzle for 500 workgroups (q=62, r=4)
    int xcd = p & 7, jj = p >> 3;
    int wg = (xcd < 4 ? xcd * 63 : 252 + (xcd - 4) * 62) + jj;
    int mt = wg & 3, nt = wg >> 2;     // neighbors share nt -> W L2 reuse
    int m0 = mt * 256, v0 = nt * 256;

    int lane = tid & 63, w = tid >> 6;
    int wm = w & 1, wn = w >> 1;       // 2 (M) x 4 (N) waves; wave owns 128x64

    // ---- staging addresses (T2: pre-swizzled global source, linear LDS dest)
    int rsub = lane >> 3;                  // row within 8-row group
    int csw = (lane & 7) ^ rsub;           // swizzled 16B-chunk index
    const unsigned short* gA = Abf + (size_t)(m0 + w * 8 + rsub) * DD + csw * 8;
    const unsigned short* gB = Wbf + (size_t)(v0 + w * 8 + rsub) * DD + csw * 8;
    int lds_w = w * 512;                   // wave-uniform LDS elem offset per issue

#define STAGE(sl, t) do {                                                              \
    unsigned short* As_ = lds + (sl) * 32768;                                          \
    unsigned short* Bs_ = lds + 16384 + (sl) * 32768;                                  \
    int k0_ = (t) * Bk;                                                                \
    _Pragma("unroll")                                                                  \
    for (int q = 0; q < 4; ++q)                                                        \
        __builtin_amdgcn_global_load_lds(                                              \
            (const __attribute__((address_space(1))) void*)(gA + (size_t)(q * 64) * DD + k0_), \
            (__attribute__((address_space(3))) void*)(As_ + q * 4096 + lds_w), 16, 0, 0); \
    _Pragma("unroll")                                                                  \
    for (int q = 0; q < 4; ++q)                                                        \
        __builtin_amdgcn_global_load_lds(                                              \
            (const __attribute__((address_space(1))) void*)(gB + (size_t)(q * 64) * DD + k0_), \
            (__attribute__((address_space(3))) void*)(Bs_ + q * 4096 + lds_w), 16, 0, 0); \
} while (0)

    // ---- fragment read offsets (swizzled chunk on read)
    int lr = lane & 15, kg = lane >> 4, l7 = lane & 7;

    f32x4 acc[8][4] = {};

    // prologue: stage tiles 0 and 1
    STAGE(0, 0);
    STAGE(1, 1);
    asm volatile("s_waitcnt vmcnt(8)" ::: "memory");   // tile 0 landed
    __builtin_amdgcn_s_barrier();

#pragma unroll 2
    for (int t = 0; t < NKT; ++t) {
        int sl = t & 1;
        unsigned short* As_ = lds + sl * 32768;
        unsigned short* Bs_ = lds + 16384 + sl * 32768;

        short8v af[2][8], bfr[2][4];
#pragma unroll
        for (int ks = 0; ks < 2; ++ks) {
            int chunk = ((ks * 4 + kg) ^ l7) * 8;
#pragma unroll
            for (int i = 0; i < 8; ++i)
                af[ks][i] = *reinterpret_cast<const short8v*>(
                    &As_[(wm * 128 + i * 16 + lr) * 64 + chunk]);
#pragma unroll
            for (int j = 0; j < 4; ++j)
                bfr[ks][j] = *reinterpret_cast<const short8v*>(
                    &Bs_[(wn * 64 + j * 16 + lr) * 64 + chunk]);
        }
        asm volatile("s_waitcnt lgkmcnt(0)" ::: "memory");  // reads done
        __builtin_amdgcn_s_barrier();                        // slot[sl] now free

        if (t + 2 < NKT) STAGE(sl, t + 2);                   // prefetch into freed slot

        __builtin_amdgcn_s_setprio(1);
#pragma unroll
        for (int i = 0; i < 8; ++i)
#pragma unroll
            for (int j = 0; j < 4; ++j) {
                acc[i][j] = __builtin_amdgcn_mfma_f32_16x16x32_bf16(af[0][i], bfr[0][j], acc[i][j], 0, 0, 0);
                acc[i][j] = __builtin_amdgcn_mfma_f32_16x16x32_bf16(af[1][i], bfr[1][j], acc[i][j], 0, 0, 0);
            }
        __builtin_amdgcn_s_setprio(0);

        if (t + 1 < NKT) {
            if (t + 2 < NKT)
                asm volatile("s_waitcnt vmcnt(8)" ::: "memory");  // tile t+1 landed, t+2 in flight
            else
                asm volatile("s_waitcnt vmcnt(0)" ::: "memory");  // last tile: drain
            __builtin_amdgcn_s_barrier();
        }
    }
#undef STAGE

    // ---- epilogue: bias + store + per-row exp-sum atomics
    int colb = lane & 15, rgrp = lane >> 4;
#pragma unroll
    for (int i = 0; i < 8; ++i) {
        float es0 = 0.f, es1 = 0.f, es2 = 0.f, es3 = 0.f;
        int gmb = m0 + wm * 128 + i * 16 + rgrp * 4;
#pragma unroll
        for (int j = 0; j < 4; ++j) {
            int gv = v0 + wn * 64 + j * 16 + colb;
            float bgj = bgen[gv];
            float v0f = acc[i][j][0] + bgj;
            float v1f = acc[i][j][1] + bgj;
            float v2f = acc[i][j][2] + bgj;
            float v3f = acc[i][j][3] + bgj;
            out[(size_t)(gmb + 0) * VV + gv] = v0f;
            out[(size_t)(gmb + 1) * VV + gv] = v1f;
            out[(size_t)(gmb + 2) * VV + gv] = v2f;
            out[(size_t)(gmb + 3) * VV + gv] = v3f;
            es0 += __expf(v0f); es1 += __expf(v1f);
            es2 += __expf(v2f); es3 += __expf(v3f);
        }
        float es[4] = {es0, es1, es2, es3};
#pragma unroll
        for (int rr = 0; rr < 4; ++rr) {
            float e = es[rr];
            e += __shfl_xor(e, 1); e += __shfl_xor(e, 2);
            e += __shfl_xor(e, 4); e += __shfl_xor(e, 8);
            if (colb == 0) atomicAdd(&zg[gmb + rr], e);
        }
    }
}

// ---------------- fallback GEMM (f32 inputs, in-register cast, 128^2) ----------------
#define FBb 128
#define FLDK 40

__global__ __launch_bounds__(256) void k_gemm_f32(const float* __restrict__ A,
                                                  const float* __restrict__ Wg,
                                                  const float* __restrict__ bgen,
                                                  float* __restrict__ out,
                                                  float* __restrict__ zg) {
    __shared__ unsigned short As[FBb * FLDK];
    __shared__ unsigned short Bs[FBb * FLDK];
    int tid = threadIdx.x;
    int bid = blockIdx.x;
    int mt = bid & 7;
    int nt = bid >> 3;
    int m0 = mt * FBb, v0 = nt * FBb;
    int lane = tid & 63, wid = tid >> 6;
    int wr = (wid >> 1) * 64, wc = (wid & 1) * 64;
    int lr = lane & 15, lk = (lane >> 4) << 3;
    int r = tid >> 1, c0 = (tid & 1) << 4;

    f32x4 acc[4][4] = {};

    for (int k0 = 0; k0 < DD; k0 += 32) {
        {
            const float4* pa = reinterpret_cast<const float4*>(A + (size_t)(m0 + r) * DD + k0 + c0);
            float4 x0 = pa[0], x1 = pa[1], x2 = pa[2], x3 = pa[3];
            ushort8v u0, u1;
            u0[0] = f2bf(x0.x); u0[1] = f2bf(x0.y); u0[2] = f2bf(x0.z); u0[3] = f2bf(x0.w);
            u0[4] = f2bf(x1.x); u0[5] = f2bf(x1.y); u0[6] = f2bf(x1.z); u0[7] = f2bf(x1.w);
            u1[0] = f2bf(x2.x); u1[1] = f2bf(x2.y); u1[2] = f2bf(x2.z); u1[3] = f2bf(x2.w);
            u1[4] = f2bf(x3.x); u1[5] = f2bf(x3.y); u1[6] = f2bf(x3.z); u1[7] = f2bf(x3.w);
            *reinterpret_cast<ushort8v*>(&As[r * FLDK + c0]) = u0;
            *reinterpret_cast<ushort8v*>(&As[r * FLDK + c0 + 8]) = u1;

            const float4* pb = reinterpret_cast<const float4*>(Wg + (size_t)(v0 + r) * DD + k0 + c0);
            float4 y0 = pb[0], y1 = pb[1], y2 = pb[2], y3 = pb[3];
            ushort8v w0, w1;
            w0[0] = f2bf(y0.x); w0[1] = f2bf(y0.y); w0[2] = f2bf(y0.z); w0[3] = f2bf(y0.w);
            w0[4] = f2bf(y1.x); w0[5] = f2bf(y1.y); w0[6] = f2bf(y1.z); w0[7] = f2bf(y1.w);
            w1[0] = f2bf(y2.x); w1[1] = f2bf(y2.y); w1[2] = f2bf(y2.z); w1[3] = f2bf(y2.w);
            w1[4] = f2bf(y3.x); w1[5] = f2bf(y3.y); w1[6] = f2bf(y3.z); w1[7] = f2bf(y3.w);
            *reinterpret_cast<ushort8v*>(&Bs[r * FLDK + c0]) = w0;
            *reinterpret_cast<ushort8v*>(&Bs[r * FLDK + c0 + 8]) = w1;
        }
        __syncthreads();

        short8v af[4], bfr[4];
#pragma unroll
        for (int i = 0; i < 4; ++i)
            af[i] = *reinterpret_cast<const short8v*>(&As[(wr + i * 16 + lr) * FLDK + lk]);
#pragma unroll
        for (int j = 0; j < 4; ++j)
            bfr[j] = *reinterpret_cast<const short8v*>(&Bs[(wc + j * 16 + lr) * FLDK + lk]);
#pragma unroll
        for (int i = 0; i < 4; ++i)
#pragma unroll
            for (int j = 0; j < 4; ++j)
                acc[i][j] = __builtin_amdgcn_mfma_f32_16x16x32_bf16(af[i], bfr[j], acc[i][j], 0, 0, 0);
        __syncthreads();
    }

    int colb = lane & 15;
    int rgrp = lane >> 4;
#pragma unroll
    for (int i = 0; i < 4; ++i) {
        float es0 = 0.f, es1 = 0.f, es2 = 0.f, es3 = 0.f;
        int gmb = m0 + wr + i * 16 + rgrp * 4;
#pragma unroll
        for (int j = 0; j < 4; ++j) {
            int gv = v0 + wc + j * 16 + colb;
            float bgj = bgen[gv];
            float v0f = acc[i][j][0] + bgj;
            float v1f = acc[i][j][1] + bgj;
            float v2f = acc[i][j][2] + bgj;
            float v3f = acc[i][j][3] + bgj;
            out[(size_t)(gmb + 0) * VV + gv] = v0f;
            out[(size_t)(gmb + 1) * VV + gv] = v1f;
            out[(size_t)(gmb + 2) * VV + gv] = v2f;
            out[(size_t)(gmb + 3) * VV + gv] = v3f;
            es0 += __expf(v0f); es1 += __expf(v1f);
            es2 += __expf(v2f); es3 += __expf(v3f);
        }
        float es[4] = {es0, es1, es2, es3};
#pragma unroll
        for (int rr = 0; rr < 4; ++rr) {
            float e = es[rr];
            e += __shfl_xor(e, 1); e += __shfl_xor(e, 2);
            e += __shfl_xor(e, 4); e += __shfl_xor(e, 8);
            if (colb == 0) atomicAdd(&zg[gmb + rr], e);
        }
    }
}

// ---------------- final combine, in place over d_out (gm = 0) ----------------
__global__ __launch_bounds__(256) void k_final(float* __restrict__ gen,
                                               const int* __restrict__ pos_map,
                                               const float* __restrict__ e_vals,
                                               const float* __restrict__ prob,
                                               const float* __restrict__ zc,
                                               const float* __restrict__ c0,
                                               const float* __restrict__ zg) {
    int m = blockIdx.x;
    int b = m >> 7;
    int tid = threadIdx.x;
    float p = prob[m];
    float A1 = p / zg[m];
    float A2 = (1.0f - p) / zc[m];
    float cc = c0[m];
    const float* ev = e_vals + (size_t)m * SS;
    float4* row = reinterpret_cast<float4*>(gen + (size_t)m * VV);
    const int4* pm = reinterpret_cast<const int4*>(pos_map + b * VV);
    for (int i = tid; i < VV / 4; i += 256) {
        float4 g = row[i];
        int4 rp = pm[i];
        float4 o;
        o.x = __logf(A1 * __expf(g.x) + A2 * ((rp.x < SS) ? ev[rp.x] : cc));
        o.y = __logf(A1 * __expf(g.y) + A2 * ((rp.y < SS) ? ev[rp.y] : cc));
        o.z = __logf(A1 * __expf(g.z) + A2 * ((rp.z < SS) ? ev[rp.z] : cc));
        o.w = __logf(A1 * __expf(g.w) + A2 * ((rp.w < SS) ? ev[rp.w] : cc));
        row[i] = o;
    }
}

extern "C" void kernel_launch(void* const* d_in, const int* in_sizes, int n_in,
                              void* d_out, int out_size, void* d_ws, size_t ws_size,
                              hipStream_t stream) {
    const int* src = (const int*)d_in[0];
    const float* dec = (const float*)d_in[1];
    const float* dattn = (const float*)d_in[2];
    const float* mem = (const float*)d_in[3];
    const float* wgen = (const float*)d_in[4];
    const float* bgen = (const float*)d_in[5];
    const float* wprob = (const float*)d_in[6];
    const float* bprob = (const float*)d_in[7];
    float* out = (float*)d_out;
    char* ws = (char*)d_ws;

    // ws layout
    int* pos_map = (int*)(ws + 0);                       // 1,024,000 B (pad 1 MB)
    float* e_vals = (float*)(ws + 1048576);              // 2 MB
    float* mw   = (float*)(ws + 3145728);                // 16 KB
    float* dw   = (float*)(ws + 3145728 + 16384);
    float* prob = (float*)(ws + 3145728 + 20480);
    float* zc   = (float*)(ws + 3145728 + 24576);
    float* c0   = (float*)(ws + 3145728 + 28672);
    float* zg   = (float*)(ws + 3145728 + 32768);
    unsigned short* Wbf = (unsigned short*)(ws + 3211264);              // 65,536,000 B
    unsigned short* Abf = (unsigned short*)(ws + 3211264 + 65536000);   // 2 MB
    const size_t NEEDED = 3211264ull + 65536000ull + 2097152ull;

    k_pm_init<<<(BB * VV + 255) / 256, 256, 0, stream>>>(pos_map, zg);
    k_pm_build<<<BB, SS, 0, stream>>>(src, pos_map);
    k_vecdots<<<(BB * SS + MM) / 4, 256, 0, stream>>>(mem, dec, wprob, mw, dw);
    k_row<<<MM, 256, 0, stream>>>(dattn, src, pos_map, mw, dw, bprob, e_vals, prob, zc, c0);

    if (ws_size >= NEEDED) {
        k_cast<<<2048, 256, 0, stream>>>(wgen, Wbf, VV * DD / 8);
        k_cast<<<512, 256, 0, stream>>>(dec, Abf, MM * DD / 8);
        k_gemm_bf<<<(MM / 256) * (VV / 256), 512, 0, stream>>>(Abf, Wbf, bgen, out, zg);
    } else {
        k_gemm_f32<<<(MM / FBb) * (VV / FBb), 256, 0, stream>>>(dec, wgen, bgen, out, zg);
    }
    k_final<<<MM, 256, 0, stream>>>(out, pos_map, e_vals, prob, zc, c0, zg);
}

// Round 4
// 246.653 us; speedup vs baseline: 1.2630x; 1.0125x over previous
//
#include <hip/hip_runtime.h>
#include <hip/hip_bf16.h>
#include <cstddef>
#include <cstdint>

// Problem constants
#define BB 8
#define HH 16
#define TT 128
#define SS 512
#define DD 1024
#define VV 32000
#define MM (BB * TT)   // 1024 output rows

typedef float f32x4 __attribute__((ext_vector_type(4)));
typedef short short8v __attribute__((ext_vector_type(8)));
typedef unsigned short ushort8v __attribute__((ext_vector_type(8)));

__device__ __forceinline__ unsigned short f2bf(float x) {
    __hip_bfloat16 h = __float2bfloat16(x);
    return __builtin_bit_cast(unsigned short, h);
}
__device__ __forceinline__ float bf2f(unsigned short u) {
    unsigned int x = ((unsigned int)u) << 16;
    return __builtin_bit_cast(float, x);
}

__device__ __forceinline__ float wave_sum(float v) {
#pragma unroll
    for (int o = 1; o < 64; o <<= 1) v += __shfl_xor(v, o);
    return v;
}
__device__ __forceinline__ float wave_max(float v) {
#pragma unroll
    for (int o = 1; o < 64; o <<= 1) v = fmaxf(v, __shfl_xor(v, o));
    return v;
}
__device__ __forceinline__ float block_sum(float v, float* red, int tid) {
    v = wave_sum(v);
    __syncthreads();
    if ((tid & 63) == 0) red[tid >> 6] = v;
    __syncthreads();
    return red[0] + red[1] + red[2] + red[3];
}
__device__ __forceinline__ float block_max(float v, float* red, int tid) {
    v = wave_max(v);
    __syncthreads();
    if ((tid & 63) == 0) red[tid >> 6] = v;
    __syncthreads();
    return fmaxf(fmaxf(red[0], red[1]), fmaxf(red[2], red[3]));
}

// ---------------- pos_map build + zg zero ----------------
__global__ void k_pm_init(int* pos_map, float* zg) {
    int i = blockIdx.x * 256 + threadIdx.x;
    if (i < BB * VV) pos_map[i] = 0x7fffffff;
    if (i < MM) zg[i] = 0.0f;
}

__global__ void k_pm_build(const int* __restrict__ src, int* pos_map) {
    int b = blockIdx.x, s = threadIdx.x;  // 8 x 512
    int tok = src[b * SS + s];
    atomicMin(&pos_map[b * VV + tok], s);
}

// ---------------- f32 -> bf16 cast (8 elems/thread, grid-stride) ----------------
__global__ __launch_bounds__(256) void k_cast(const float* __restrict__ in,
                                              unsigned short* __restrict__ outp, int n8) {
    int stride = gridDim.x * 256;
    for (int i = blockIdx.x * 256 + threadIdx.x; i < n8; i += stride) {
        const float4* p = reinterpret_cast<const float4*>(in + (size_t)i * 8);
        float4 a = p[0], b = p[1];
        ushort8v u;
        u[0] = f2bf(a.x); u[1] = f2bf(a.y); u[2] = f2bf(a.z); u[3] = f2bf(a.w);
        u[4] = f2bf(b.x); u[5] = f2bf(b.y); u[6] = f2bf(b.z); u[7] = f2bf(b.w);
        *reinterpret_cast<ushort8v*>(outp + (size_t)i * 8) = u;
    }
}

// ---------------- mw / dw dot products ----------------
__global__ __launch_bounds__(256) void k_vecdots(const float* __restrict__ memory,
                                                 const float* __restrict__ dec,
                                                 const float* __restrict__ wprob,
                                                 float* mw, float* dw) {
    int row = blockIdx.x * 4 + (threadIdx.x >> 6);
    int lane = threadIdx.x & 63;
    const float4* srcv;
    const float4* wv;
    if (row < BB * SS) {
        srcv = reinterpret_cast<const float4*>(memory + (size_t)row * DD);
        wv = reinterpret_cast<const float4*>(wprob);
    } else {
        srcv = reinterpret_cast<const float4*>(dec + (size_t)(row - BB * SS) * DD);
        wv = reinterpret_cast<const float4*>(wprob + DD);
    }
    float sum = 0.f;
#pragma unroll
    for (int k = 0; k < 4; ++k) {
        int idx = lane + 64 * k;
        float4 a = srcv[idx];
        float4 w = wv[idx];
        sum += a.x * w.x + a.y * w.y + a.z * w.z + a.w * w.w;
    }
    sum = wave_sum(sum);
    if (lane == 0) {
        if (row < BB * SS) mw[row] = sum;
        else dw[row - BB * SS] = sum;
    }
}

// ---------------- per-(b,t) row: attn mean, scatter, prob, copy-Z ----------------
__global__ __launch_bounds__(256) void k_row(const float* __restrict__ dattn,
                                             const int* __restrict__ src,
                                             const int* __restrict__ pos_map,
                                             const float* __restrict__ mw,
                                             const float* __restrict__ dw,
                                             const float* __restrict__ bprob,
                                             float* __restrict__ e_vals,
                                             float* __restrict__ prob,
                                             float* __restrict__ zc,
                                             float* __restrict__ c0) {
    int bt = blockIdx.x;
    int b = bt >> 7;
    int t = bt & 127;
    int tid = threadIdx.x;
    __shared__ float a_row[SS];
    __shared__ float vals[SS];
    __shared__ float red[4];

    for (int s = tid; s < SS; s += 256) {
        const float* base = dattn + ((size_t)b * HH * TT + t) * SS + s;
        float sum = 0.f;
#pragma unroll
        for (int h = 0; h < HH; ++h) sum += base[(size_t)h * TT * SS];
        a_row[s] = sum * 0.0625f;
        vals[s] = 0.f;
    }
    __syncthreads();
    for (int s = tid; s < SS; s += 256) {
        int rep = pos_map[b * VV + src[b * SS + s]];
        atomicAdd(&vals[rep], a_row[s]);
    }
    __syncthreads();
    float psum = 0.f;
    for (int s = tid; s < SS; s += 256) psum += a_row[s] * mw[b * SS + s];
    psum = block_sum(psum, red, tid);
    float z = psum + dw[bt] + bprob[0];
    float p = 1.0f / (1.0f + __expf(-z));
    float mxv = -3.4e38f;
    for (int s = tid; s < SS; s += 256) {
        int rep = pos_map[b * VV + src[b * SS + s]];
        if (rep == s) mxv = fmaxf(mxv, vals[s]);
    }
    mxv = block_max(mxv, red, tid);
    float m_c = fmaxf(0.0f, mxv);
    float sexp = 0.f, cnt = 0.f;
    for (int s = tid; s < SS; s += 256) {
        int rep = pos_map[b * VV + src[b * SS + s]];
        float e = 0.0f;
        if (rep == s) {
            e = __expf(vals[s] - m_c);
            sexp += e;
            cnt += 1.0f;
        }
        e_vals[(size_t)bt * SS + s] = e;
    }
    sexp = block_sum(sexp, red, tid);
    cnt = block_sum(cnt, red, tid);
    if (tid == 0) {
        prob[bt] = p;
        zc[bt] = ((float)VV - cnt) * __expf(-m_c) + sexp;
        c0[bt] = __expf(-m_c);
    }
}

// =====================================================================
// 256x256 bf16 MFMA GEMM, 8 waves, BK=64, dbuf LDS, 8-phase interleave
// (4 phases/K-tile), counted vmcnt(4) at tile boundaries only. T1-T5.
// EPI=0: store f32 logits to out. EPI=1: store bf16 exp(logit) to ebuf.
// =====================================================================
#define Bk 64
#define NKT 16   // K tiles = 1024/64

template <int EPI>
__global__ __launch_bounds__(512, 2) void k_gemm_bf(const unsigned short* __restrict__ Abf,
                                                    const unsigned short* __restrict__ Wbf,
                                                    const float* __restrict__ bgen,
                                                    float* __restrict__ out,
                                                    unsigned short* __restrict__ ebuf,
                                                    float* __restrict__ zg) {
    // 128 KiB LDS: [As0 32K][Bs0 32K][As1 32K][Bs1 32K] bytes (ushort elems)
    __shared__ unsigned short lds[65536];

    int tid = threadIdx.x;
    int p = blockIdx.x;
    // m204 bijective XCD swizzle for 500 workgroups (q=62, r=4)
    int xcd = p & 7, jj = p >> 3;
    int wg = (xcd < 4 ? xcd * 63 : 252 + (xcd - 4) * 62) + jj;
    int mt = wg & 3, nt = wg >> 2;     // neighbors share nt -> W L2 reuse
    int m0 = mt * 256, v0 = nt * 256;

    int lane = tid & 63, w = tid >> 6;
    int wm = w & 1, wn = w >> 1;       // 2 (M) x 4 (N) waves; wave owns 128x64

    // ---- staging addresses (T2: pre-swizzled global source, linear LDS dest)
    int rsub = lane >> 3;                  // row within 8-row group
    int csw = (lane & 7) ^ rsub;           // swizzled 16B-chunk index
    const unsigned short* gA = Abf + (size_t)(m0 + w * 8 + rsub) * DD + csw * 8;
    const unsigned short* gB = Wbf + (size_t)(v0 + w * 8 + rsub) * DD + csw * 8;
    int lds_w = w * 512;                   // wave-uniform LDS elem offset per issue

#define STAGE_A(SL, T, Q)                                                                     \
    __builtin_amdgcn_global_load_lds(                                                         \
        (const __attribute__((address_space(1))) void*)(gA + (size_t)((Q) * 64) * DD + (T) * Bk), \
        (__attribute__((address_space(3))) void*)(lds + (SL) * 32768 + (Q) * 4096 + lds_w), 16, 0, 0)
#define STAGE_B(SL, T, Q)                                                                     \
    __builtin_amdgcn_global_load_lds(                                                         \
        (const __attribute__((address_space(1))) void*)(gB + (size_t)((Q) * 64) * DD + (T) * Bk), \
        (__attribute__((address_space(3))) void*)(lds + 16384 + (SL) * 32768 + (Q) * 4096 + lds_w), 16, 0, 0)

    // ---- fragment read offsets (swizzled chunk on read)
    int lr = lane & 15, kg = lane >> 4, l7 = lane & 7;

    f32x4 acc[8][4] = {};

    // prologue: stage tiles 0 and 1 (8 issues each, tile-grouped for vmcnt order)
#pragma unroll
    for (int q = 0; q < 4; ++q) STAGE_B(0, 0, q);
#pragma unroll
    for (int q = 0; q < 4; ++q) STAGE_A(0, 0, q);
#pragma unroll
    for (int q = 0; q < 4; ++q) STAGE_B(1, 1, q);
#pragma unroll
    for (int q = 0; q < 4; ++q) STAGE_A(1, 1, q);
    asm volatile("s_waitcnt vmcnt(8)" ::: "memory");   // tile 0 landed
    __builtin_amdgcn_s_barrier();

#pragma unroll 2
    for (int t = 0; t < NKT; ++t) {
        const int sl = t & 1;
        unsigned short* As_ = lds + sl * 32768;
        unsigned short* Bs_ = lds + 16384 + sl * 32768;
        short8v af[4], bfr[4];
        const bool stA = (t >= 1) && (t + 1 < NKT);  // A(t+1) into slot sl^1

        // ===== phase 0: ks=0, ih=0 (8 ds_read + 2 stage) =====
        {
            const int chunk = (kg ^ l7) * 8;
#pragma unroll
            for (int j = 0; j < 4; ++j)
                bfr[j] = *reinterpret_cast<const short8v*>(&Bs_[(wn * 64 + j * 16 + lr) * 64 + chunk]);
#pragma unroll
            for (int i = 0; i < 4; ++i)
                af[i] = *reinterpret_cast<const short8v*>(&As_[(wm * 128 + i * 16 + lr) * 64 + chunk]);
            if (stA) { STAGE_A(sl ^ 1, t + 1, 0); STAGE_A(sl ^ 1, t + 1, 2); }
            __builtin_amdgcn_s_barrier();
            asm volatile("s_waitcnt lgkmcnt(0)" ::: "memory");
            __builtin_amdgcn_sched_barrier(0);
            __builtin_amdgcn_s_setprio(1);
#pragma unroll
            for (int i = 0; i < 4; ++i)
#pragma unroll
                for (int j = 0; j < 4; ++j)
                    acc[i][j] = __builtin_amdgcn_mfma_f32_16x16x32_bf16(af[i], bfr[j], acc[i][j], 0, 0, 0);
            __builtin_amdgcn_s_setprio(0);
            __builtin_amdgcn_s_barrier();
        }
        // ===== phase 1: ks=0, ih=1 (4 ds_read + 2 stage; bfr reused) =====
        {
            const int chunk = (kg ^ l7) * 8;
#pragma unroll
            for (int i = 0; i < 4; ++i)
                af[i] = *reinterpret_cast<const short8v*>(&As_[(wm * 128 + (i + 4) * 16 + lr) * 64 + chunk]);
            if (stA) { STAGE_A(sl ^ 1, t + 1, 1); STAGE_A(sl ^ 1, t + 1, 3); }
            __builtin_amdgcn_s_barrier();
            asm volatile("s_waitcnt lgkmcnt(0)" ::: "memory");
            __builtin_amdgcn_sched_barrier(0);
            __builtin_amdgcn_s_setprio(1);
#pragma unroll
            for (int i = 0; i < 4; ++i)
#pragma unroll
                for (int j = 0; j < 4; ++j)
                    acc[i + 4][j] = __builtin_amdgcn_mfma_f32_16x16x32_bf16(af[i], bfr[j], acc[i + 4][j], 0, 0, 0);
            __builtin_amdgcn_s_setprio(0);
            __builtin_amdgcn_s_barrier();
        }
        // ===== phase 2: ks=1, ih=0 (8 ds_read) =====
        {
            const int chunk = ((4 + kg) ^ l7) * 8;
#pragma unroll
            for (int j = 0; j < 4; ++j)
                bfr[j] = *reinterpret_cast<const short8v*>(&Bs_[(wn * 64 + j * 16 + lr) * 64 + chunk]);
#pragma unroll
            for (int i = 0; i < 4; ++i)
                af[i] = *reinterpret_cast<const short8v*>(&As_[(wm * 128 + i * 16 + lr) * 64 + chunk]);
            __builtin_amdgcn_s_barrier();
            asm volatile("s_waitcnt lgkmcnt(0)" ::: "memory");
            __builtin_amdgcn_sched_barrier(0);
            __builtin_amdgcn_s_setprio(1);
#pragma unroll
            for (int i = 0; i < 4; ++i)
#pragma unroll
                for (int j = 0; j < 4; ++j)
                    acc[i][j] = __builtin_amdgcn_mfma_f32_16x16x32_bf16(af[i], bfr[j], acc[i][j], 0, 0, 0);
            __builtin_amdgcn_s_setprio(0);
            __builtin_amdgcn_s_barrier();
        }
        // ===== phase 3: ks=1, ih=1 (4 ds_read + 4 stage B(t+2)) + boundary =====
        {
            const int chunk = ((4 + kg) ^ l7) * 8;
#pragma unroll
            for (int i = 0; i < 4; ++i)
                af[i] = *reinterpret_cast<const short8v*>(&As_[(wm * 128 + (i + 4) * 16 + lr) * 64 + chunk]);
            if (t + 2 < NKT) {
                STAGE_B(sl, t + 2, 0); STAGE_B(sl, t + 2, 1);
                STAGE_B(sl, t + 2, 2); STAGE_B(sl, t + 2, 3);
            }
            __builtin_amdgcn_s_barrier();
            asm volatile("s_waitcnt lgkmcnt(0)" ::: "memory");
            __builtin_amdgcn_sched_barrier(0);
            __builtin_amdgcn_s_setprio(1);
#pragma unroll
            for (int i = 0; i < 4; ++i)
#pragma unroll
                for (int j = 0; j < 4; ++j)
                    acc[i + 4][j] = __builtin_amdgcn_mfma_f32_16x16x32_bf16(af[i], bfr[j], acc[i + 4][j], 0, 0, 0);
            __builtin_amdgcn_s_setprio(0);
            if (t + 1 < NKT) {
                if (t + 2 < NKT)
                    asm volatile("s_waitcnt vmcnt(4)" ::: "memory");  // tile t+1 fully landed
                else
                    asm volatile("s_waitcnt vmcnt(0)" ::: "memory");  // drain for last tile
                __builtin_amdgcn_s_barrier();
            }
        }
    }
#undef STAGE_A
#undef STAGE_B

    // ---- epilogue: bias + exp + store + per-row exp-sum atomics
    int colb = lane & 15, rgrp = lane >> 4;
#pragma unroll
    for (int i = 0; i < 8; ++i) {
        float es0 = 0.f, es1 = 0.f, es2 = 0.f, es3 = 0.f;
        int gmb = m0 + wm * 128 + i * 16 + rgrp * 4;
#pragma unroll
        for (int j = 0; j < 4; ++j) {
            int gv = v0 + wn * 64 + j * 16 + colb;
            float bgj = bgen[gv];
            float v0f = acc[i][j][0] + bgj;
            float v1f = acc[i][j][1] + bgj;
            float v2f = acc[i][j][2] + bgj;
            float v3f = acc[i][j][3] + bgj;
            float e0 = __expf(v0f), e1 = __expf(v1f), e2 = __expf(v2f), e3 = __expf(v3f);
            if constexpr (EPI == 1) {
                ebuf[(size_t)(gmb + 0) * VV + gv] = f2bf(e0);
                ebuf[(size_t)(gmb + 1) * VV + gv] = f2bf(e1);
                ebuf[(size_t)(gmb + 2) * VV + gv] = f2bf(e2);
                ebuf[(size_t)(gmb + 3) * VV + gv] = f2bf(e3);
            } else {
                out[(size_t)(gmb + 0) * VV + gv] = v0f;
                out[(size_t)(gmb + 1) * VV + gv] = v1f;
                out[(size_t)(gmb + 2) * VV + gv] = v2f;
                out[(size_t)(gmb + 3) * VV + gv] = v3f;
            }
            es0 += e0; es1 += e1; es2 += e2; es3 += e3;
        }
        float es[4] = {es0, es1, es2, es3};
#pragma unroll
        for (int rr = 0; rr < 4; ++rr) {
            float e = es[rr];
            e += __shfl_xor(e, 1); e += __shfl_xor(e, 2);
            e += __shfl_xor(e, 4); e += __shfl_xor(e, 8);
            if (colb == 0) atomicAdd(&zg[gmb + rr], e);
        }
    }
}

// ---------------- fallback GEMM (f32 inputs, in-register cast, 128^2) ----------------
#define FBb 128
#define FLDK 40

__global__ __launch_bounds__(256) void k_gemm_f32(const float* __restrict__ A,
                                                  const float* __restrict__ Wg,
                                                  const float* __restrict__ bgen,
                                                  float* __restrict__ out,
                                                  float* __restrict__ zg) {
    __shared__ unsigned short As[FBb * FLDK];
    __shared__ unsigned short Bs[FBb * FLDK];
    int tid = threadIdx.x;
    int bid = blockIdx.x;
    int mt = bid & 7;
    int nt = bid >> 3;
    int m0 = mt * FBb, v0 = nt * FBb;
    int lane = tid & 63, wid = tid >> 6;
    int wr = (wid >> 1) * 64, wc = (wid & 1) * 64;
    int lr = lane & 15, lk = (lane >> 4) << 3;
    int r = tid >> 1, c0 = (tid & 1) << 4;

    f32x4 acc[4][4] = {};

    for (int k0 = 0; k0 < DD; k0 += 32) {
        {
            const float4* pa = reinterpret_cast<const float4*>(A + (size_t)(m0 + r) * DD + k0 + c0);
            float4 x0 = pa[0], x1 = pa[1], x2 = pa[2], x3 = pa[3];
            ushort8v u0, u1;
            u0[0] = f2bf(x0.x); u0[1] = f2bf(x0.y); u0[2] = f2bf(x0.z); u0[3] = f2bf(x0.w);
            u0[4] = f2bf(x1.x); u0[5] = f2bf(x1.y); u0[6] = f2bf(x1.z); u0[7] = f2bf(x1.w);
            u1[0] = f2bf(x2.x); u1[1] = f2bf(x2.y); u1[2] = f2bf(x2.z); u1[3] = f2bf(x2.w);
            u1[4] = f2bf(x3.x); u1[5] = f2bf(x3.y); u1[6] = f2bf(x3.z); u1[7] = f2bf(x3.w);
            *reinterpret_cast<ushort8v*>(&As[r * FLDK + c0]) = u0;
            *reinterpret_cast<ushort8v*>(&As[r * FLDK + c0 + 8]) = u1;

            const float4* pb = reinterpret_cast<const float4*>(Wg + (size_t)(v0 + r) * DD + k0 + c0);
            float4 y0 = pb[0], y1 = pb[1], y2 = pb[2], y3 = pb[3];
            ushort8v w0, w1;
            w0[0] = f2bf(y0.x); w0[1] = f2bf(y0.y); w0[2] = f2bf(y0.z); w0[3] = f2bf(y0.w);
            w0[4] = f2bf(y1.x); w0[5] = f2bf(y1.y); w0[6] = f2bf(y1.z); w0[7] = f2bf(y1.w);
            w1[0] = f2bf(y2.x); w1[1] = f2bf(y2.y); w1[2] = f2bf(y2.z); w1[3] = f2bf(y2.w);
            w1[4] = f2bf(y3.x); w1[5] = f2bf(y3.y); w1[6] = f2bf(y3.z); w1[7] = f2bf(y3.w);
            *reinterpret_cast<ushort8v*>(&Bs[r * FLDK + c0]) = w0;
            *reinterpret_cast<ushort8v*>(&Bs[r * FLDK + c0 + 8]) = w1;
        }
        __syncthreads();

        short8v af[4], bfr[4];
#pragma unroll
        for (int i = 0; i < 4; ++i)
            af[i] = *reinterpret_cast<const short8v*>(&As[(wr + i * 16 + lr) * FLDK + lk]);
#pragma unroll
        for (int j = 0; j < 4; ++j)
            bfr[j] = *reinterpret_cast<const short8v*>(&Bs[(wc + j * 16 + lr) * FLDK + lk]);
#pragma unroll
        for (int i = 0; i < 4; ++i)
#pragma unroll
            for (int j = 0; j < 4; ++j)
                acc[i][j] = __builtin_amdgcn_mfma_f32_16x16x32_bf16(af[i], bfr[j], acc[i][j], 0, 0, 0);
        __syncthreads();
    }

    int colb = lane & 15;
    int rgrp = lane >> 4;
#pragma unroll
    for (int i = 0; i < 4; ++i) {
        float es0 = 0.f, es1 = 0.f, es2 = 0.f, es3 = 0.f;
        int gmb = m0 + wr + i * 16 + rgrp * 4;
#pragma unroll
        for (int j = 0; j < 4; ++j) {
            int gv = v0 + wc + j * 16 + colb;
            float bgj = bgen[gv];
            float v0f = acc[i][j][0] + bgj;
            float v1f = acc[i][j][1] + bgj;
            float v2f = acc[i][j][2] + bgj;
            float v3f = acc[i][j][3] + bgj;
            out[(size_t)(gmb + 0) * VV + gv] = v0f;
            out[(size_t)(gmb + 1) * VV + gv] = v1f;
            out[(size_t)(gmb + 2) * VV + gv] = v2f;
            out[(size_t)(gmb + 3) * VV + gv] = v3f;
            es0 += __expf(v0f); es1 += __expf(v1f);
            es2 += __expf(v2f); es3 += __expf(v3f);
        }
        float es[4] = {es0, es1, es2, es3};
#pragma unroll
        for (int rr = 0; rr < 4; ++rr) {
            float e = es[rr];
            e += __shfl_xor(e, 1); e += __shfl_xor(e, 2);
            e += __shfl_xor(e, 4); e += __shfl_xor(e, 8);
            if (colb == 0) atomicAdd(&zg[gmb + rr], e);
        }
    }
}

// ---------------- final combine into d_out ----------------
// RD16=1: read bf16 exp(logit) from ebuf. RD16=0: read f32 logits from gen (in place).
template <int RD16>
__global__ __launch_bounds__(256) void k_final(float* __restrict__ gen,
                                               const unsigned short* __restrict__ ebuf,
                                               const int* __restrict__ pos_map,
                                               const float* __restrict__ e_vals,
                                               const float* __restrict__ prob,
                                               const float* __restrict__ zc,
                                               const float* __restrict__ c0,
                                               const float* __restrict__ zg) {
    int m = blockIdx.x;
    int b = m >> 7;
    int tid = threadIdx.x;
    float p = prob[m];
    float A1 = p / zg[m];
    float A2 = (1.0f - p) / zc[m];
    float cc = c0[m];
    const float* ev = e_vals + (size_t)m * SS;
    float4* row = reinterpret_cast<float4*>(gen + (size_t)m * VV);
    const int4* pm = reinterpret_cast<const int4*>(pos_map + b * VV);
    if constexpr (RD16 == 1) {
        const ushort4* erow = reinterpret_cast<const ushort4*>(ebuf + (size_t)m * VV);
        for (int i = tid; i < VV / 4; i += 256) {
            ushort4 ee = erow[i];
            int4 rp = pm[i];
            float4 o;
            o.x = __logf(A1 * bf2f(ee.x) + A2 * ((rp.x < SS) ? ev[rp.x] : cc));
            o.y = __logf(A1 * bf2f(ee.y) + A2 * ((rp.y < SS) ? ev[rp.y] : cc));
            o.z = __logf(A1 * bf2f(ee.z) + A2 * ((rp.z < SS) ? ev[rp.z] : cc));
            o.w = __logf(A1 * bf2f(ee.w) + A2 * ((rp.w < SS) ? ev[rp.w] : cc));
            row[i] = o;
        }
    } else {
        for (int i = tid; i < VV / 4; i += 256) {
            float4 g = row[i];
            int4 rp = pm[i];
            float4 o;
            o.x = __logf(A1 * __expf(g.x) + A2 * ((rp.x < SS) ? ev[rp.x] : cc));
            o.y = __logf(A1 * __expf(g.y) + A2 * ((rp.y < SS) ? ev[rp.y] : cc));
            o.z = __logf(A1 * __expf(g.z) + A2 * ((rp.z < SS) ? ev[rp.z] : cc));
            o.w = __logf(A1 * __expf(g.w) + A2 * ((rp.w < SS) ? ev[rp.w] : cc));
            row[i] = o;
        }
    }
}

extern "C" void kernel_launch(void* const* d_in, const int* in_sizes, int n_in,
                              void* d_out, int out_size, void* d_ws, size_t ws_size,
                              hipStream_t stream) {
    const int* src = (const int*)d_in[0];
    const float* dec = (const float*)d_in[1];
    const float* dattn = (const float*)d_in[2];
    const float* mem = (const float*)d_in[3];
    const float* wgen = (const float*)d_in[4];
    const float* bgen = (const float*)d_in[5];
    const float* wprob = (const float*)d_in[6];
    const float* bprob = (const float*)d_in[7];
    float* out = (float*)d_out;
    char* ws = (char*)d_ws;

    // ws layout
    int* pos_map = (int*)(ws + 0);                       // 1,024,000 B (pad 1 MB)
    float* e_vals = (float*)(ws + 1048576);              // 2 MB
    float* mw   = (float*)(ws + 3145728);                // 16 KB
    float* dw   = (float*)(ws + 3145728 + 16384);
    float* prob = (float*)(ws + 3145728 + 20480);
    float* zc   = (float*)(ws + 3145728 + 24576);
    float* c0   = (float*)(ws + 3145728 + 28672);
    float* zg   = (float*)(ws + 3145728 + 32768);
    unsigned short* Wbf = (unsigned short*)(ws + 3211264);              // 65,536,000 B
    unsigned short* Abf = (unsigned short*)(ws + 3211264 + 65536000);   // 2 MB
    unsigned short* Ebf = (unsigned short*)(ws + 3211264 + 65536000 + 2097152);  // 65,536,000 B
    const size_t NEEDED  = 3211264ull + 65536000ull + 2097152ull;
    const size_t NEEDED2 = NEEDED + 65536000ull;

    k_pm_init<<<(BB * VV + 255) / 256, 256, 0, stream>>>(pos_map, zg);
    k_pm_build<<<BB, SS, 0, stream>>>(src, pos_map);
    k_vecdots<<<(BB * SS + MM) / 4, 256, 0, stream>>>(mem, dec, wprob, mw, dw);
    k_row<<<MM, 256, 0, stream>>>(dattn, src, pos_map, mw, dw, bprob, e_vals, prob, zc, c0);

    if (ws_size >= NEEDED) {
        k_cast<<<2048, 256, 0, stream>>>(wgen, Wbf, VV * DD / 8);
        k_cast<<<512, 256, 0, stream>>>(dec, Abf, MM * DD / 8);
        if (ws_size >= NEEDED2) {
            k_gemm_bf<1><<<(MM / 256) * (VV / 256), 512, 0, stream>>>(Abf, Wbf, bgen, out, Ebf, zg);
            k_final<1><<<MM, 256, 0, stream>>>(out, Ebf, pos_map, e_vals, prob, zc, c0, zg);
        } else {
            k_gemm_bf<0><<<(MM / 256) * (VV / 256), 512, 0, stream>>>(Abf, Wbf, bgen, out, Ebf, zg);
            k_final<0><<<MM, 256, 0, stream>>>(out, Ebf, pos_map, e_vals, prob, zc, c0, zg);
        }
    } else {
        k_gemm_f32<<<(MM / FBb) * (VV / FBb), 256, 0, stream>>>(dec, wgen, bgen, out, zg);
        k_final<0><<<MM, 256, 0, stream>>>(out, Ebf, pos_map, e_vals, prob, zc, c0, zg);
    }
}

// Round 5
// 230.119 us; speedup vs baseline: 1.3537x; 1.0718x over previous
//
#include <hip/hip_runtime.h>
#include <hip/hip_bf16.h>
#include <cstddef>
#include <cstdint>

// Problem constants
#define BB 8
#define HH 16
#define TT 128
#define SS 512
#define DD 1024
#define VV 32000
#define MM (BB * TT)   // 1024 output rows

typedef float f32x4 __attribute__((ext_vector_type(4)));
typedef short short8v __attribute__((ext_vector_type(8)));
typedef unsigned short ushort8v __attribute__((ext_vector_type(8)));

__device__ __forceinline__ unsigned short f2bf(float x) {
    __hip_bfloat16 h = __float2bfloat16(x);
    return __builtin_bit_cast(unsigned short, h);
}
__device__ __forceinline__ float bf2f(unsigned short u) {
    unsigned int x = ((unsigned int)u) << 16;
    return __builtin_bit_cast(float, x);
}

__device__ __forceinline__ float wave_sum(float v) {
#pragma unroll
    for (int o = 1; o < 64; o <<= 1) v += __shfl_xor(v, o);
    return v;
}
__device__ __forceinline__ float wave_max(float v) {
#pragma unroll
    for (int o = 1; o < 64; o <<= 1) v = fmaxf(v, __shfl_xor(v, o));
    return v;
}
__device__ __forceinline__ float block_sum(float v, float* red, int tid) {
    v = wave_sum(v);
    __syncthreads();
    if ((tid & 63) == 0) red[tid >> 6] = v;
    __syncthreads();
    return red[0] + red[1] + red[2] + red[3];
}
__device__ __forceinline__ float block_max(float v, float* red, int tid) {
    v = wave_max(v);
    __syncthreads();
    if ((tid & 63) == 0) red[tid >> 6] = v;
    __syncthreads();
    return fmaxf(fmaxf(red[0], red[1]), fmaxf(red[2], red[3]));
}

// ---------------- pos_map build + zg zero ----------------
__global__ void k_pm_init(int* pos_map, float* zg) {
    int i = blockIdx.x * 256 + threadIdx.x;
    if (i < BB * VV) pos_map[i] = 0x7fffffff;
    if (i < MM) zg[i] = 0.0f;
}

__global__ void k_pm_build(const int* __restrict__ src, int* pos_map) {
    int b = blockIdx.x, s = threadIdx.x;  // 8 x 512
    int tok = src[b * SS + s];
    atomicMin(&pos_map[b * VV + tok], s);
}

// ---------------- f32 -> bf16 cast (8 elems/thread, grid-stride) ----------------
__global__ __launch_bounds__(256) void k_cast(const float* __restrict__ in,
                                              unsigned short* __restrict__ outp, int n8) {
    int stride = gridDim.x * 256;
    for (int i = blockIdx.x * 256 + threadIdx.x; i < n8; i += stride) {
        const float4* p = reinterpret_cast<const float4*>(in + (size_t)i * 8);
        float4 a = p[0], b = p[1];
        ushort8v u;
        u[0] = f2bf(a.x); u[1] = f2bf(a.y); u[2] = f2bf(a.z); u[3] = f2bf(a.w);
        u[4] = f2bf(b.x); u[5] = f2bf(b.y); u[6] = f2bf(b.z); u[7] = f2bf(b.w);
        *reinterpret_cast<ushort8v*>(outp + (size_t)i * 8) = u;
    }
}

// ---------------- mw / dw dot products ----------------
__global__ __launch_bounds__(256) void k_vecdots(const float* __restrict__ memory,
                                                 const float* __restrict__ dec,
                                                 const float* __restrict__ wprob,
                                                 float* mw, float* dw) {
    int row = blockIdx.x * 4 + (threadIdx.x >> 6);
    int lane = threadIdx.x & 63;
    const float4* srcv;
    const float4* wv;
    if (row < BB * SS) {
        srcv = reinterpret_cast<const float4*>(memory + (size_t)row * DD);
        wv = reinterpret_cast<const float4*>(wprob);
    } else {
        srcv = reinterpret_cast<const float4*>(dec + (size_t)(row - BB * SS) * DD);
        wv = reinterpret_cast<const float4*>(wprob + DD);
    }
    float sum = 0.f;
#pragma unroll
    for (int k = 0; k < 4; ++k) {
        int idx = lane + 64 * k;
        float4 a = srcv[idx];
        float4 w = wv[idx];
        sum += a.x * w.x + a.y * w.y + a.z * w.z + a.w * w.w;
    }
    sum = wave_sum(sum);
    if (lane == 0) {
        if (row < BB * SS) mw[row] = sum;
        else dw[row - BB * SS] = sum;
    }
}

// ---------------- per-(b,t) row: attn mean, scatter, prob, copy-Z ----------------
__global__ __launch_bounds__(256) void k_row(const float* __restrict__ dattn,
                                             const int* __restrict__ src,
                                             const int* __restrict__ pos_map,
                                             const float* __restrict__ mw,
                                             const float* __restrict__ dw,
                                             const float* __restrict__ bprob,
                                             float* __restrict__ e_vals,
                                             float* __restrict__ prob,
                                             float* __restrict__ zc,
                                             float* __restrict__ c0) {
    int bt = blockIdx.x;
    int b = bt >> 7;
    int t = bt & 127;
    int tid = threadIdx.x;
    __shared__ float a_row[SS];
    __shared__ float vals[SS];
    __shared__ float red[4];

    for (int s = tid; s < SS; s += 256) {
        const float* base = dattn + ((size_t)b * HH * TT + t) * SS + s;
        float sum = 0.f;
#pragma unroll
        for (int h = 0; h < HH; ++h) sum += base[(size_t)h * TT * SS];
        a_row[s] = sum * 0.0625f;
        vals[s] = 0.f;
    }
    __syncthreads();
    for (int s = tid; s < SS; s += 256) {
        int rep = pos_map[b * VV + src[b * SS + s]];
        atomicAdd(&vals[rep], a_row[s]);
    }
    __syncthreads();
    float psum = 0.f;
    for (int s = tid; s < SS; s += 256) psum += a_row[s] * mw[b * SS + s];
    psum = block_sum(psum, red, tid);
    float z = psum + dw[bt] + bprob[0];
    float p = 1.0f / (1.0f + __expf(-z));
    float mxv = -3.4e38f;
    for (int s = tid; s < SS; s += 256) {
        int rep = pos_map[b * VV + src[b * SS + s]];
        if (rep == s) mxv = fmaxf(mxv, vals[s]);
    }
    mxv = block_max(mxv, red, tid);
    float m_c = fmaxf(0.0f, mxv);
    float sexp = 0.f, cnt = 0.f;
    for (int s = tid; s < SS; s += 256) {
        int rep = pos_map[b * VV + src[b * SS + s]];
        float e = 0.0f;
        if (rep == s) {
            e = __expf(vals[s] - m_c);
            sexp += e;
            cnt += 1.0f;
        }
        e_vals[(size_t)bt * SS + s] = e;
    }
    sexp = block_sum(sexp, red, tid);
    cnt = block_sum(cnt, red, tid);
    if (tid == 0) {
        prob[bt] = p;
        zc[bt] = ((float)VV - cnt) * __expf(-m_c) + sexp;
        c0[bt] = __expf(-m_c);
    }
}

// =====================================================================
// 128x256 bf16 MFMA GEMM, 8 waves (64x64 each), BK=64, single-buffer
// 48 KiB LDS -> 2 blocks/CU, 16 waves/CU (m114 inter-block overlap).
// T2 XOR-swizzle (pre-swizzled source + swizzled read). Grid 1000, 8x125
// bijective XCD swizzle. EPI=1: store bf16 exp(logit); EPI=0: f32 logits.
// =====================================================================
#define Bk 64
#define NKT 16   // K tiles = 1024/64

#define AS1 __attribute__((address_space(1)))
#define AS3 __attribute__((address_space(3)))

template <int EPI>
__global__ __launch_bounds__(512, 4) void k_gemm_bf(const unsigned short* __restrict__ Abf,
                                                    const unsigned short* __restrict__ Wbf,
                                                    const float* __restrict__ bgen,
                                                    float* __restrict__ out,
                                                    unsigned short* __restrict__ ebuf,
                                                    float* __restrict__ zg) {
    // 48 KiB: As [128][64] (8192 elems) | Bs [256][64] (16384 elems)
    __shared__ unsigned short lds[24576];

    int tid = threadIdx.x;
    int p = blockIdx.x;
    // bijective XCD swizzle: 1000 = 8 * 125
    int wg = (p & 7) * 125 + (p >> 3);
    int mt = wg & 7, nt = wg >> 3;     // consecutive wg share nt -> W L2 reuse
    int m0 = mt * 128, v0 = nt * 256;

    int lane = tid & 63, w = tid >> 6;
    int wm = w & 1, wn = w >> 1;       // wave owns 64(M) x 64(N)

    // staging: thread -> (row = tid>>3, chunk = tid&7), source pre-swizzled
    int srow = tid >> 3;               // 0..63 within each 64-row issue group
    int schunk = (tid & 7) ^ (srow & 7);
    const unsigned short* gA = Abf + (size_t)(m0 + srow) * DD + schunk * 8;
    const unsigned short* gB = Wbf + (size_t)(v0 + srow) * DD + schunk * 8;

#define STAGE(T) do {                                                                  \
    size_t ko_ = (size_t)(T) * Bk;                                                     \
    _Pragma("unroll")                                                                  \
    for (int q = 0; q < 2; ++q)                                                        \
        __builtin_amdgcn_global_load_lds(                                              \
            (const AS1 void*)(gA + (size_t)q * 64 * DD + ko_),                         \
            (AS3 void*)(lds + q * 4096 + tid * 8), 16, 0, 0);                          \
    _Pragma("unroll")                                                                  \
    for (int q = 0; q < 4; ++q)                                                        \
        __builtin_amdgcn_global_load_lds(                                              \
            (const AS1 void*)(gB + (size_t)q * 64 * DD + ko_),                         \
            (AS3 void*)(lds + 8192 + q * 4096 + tid * 8), 16, 0, 0);                   \
} while (0)

    int lr = lane & 15, kg = lane >> 4, l7s = (lane & 15) & 7;

    f32x4 acc[4][4] = {};

    STAGE(0);
    asm volatile("s_waitcnt vmcnt(0)" ::: "memory");
    __builtin_amdgcn_s_barrier();

    for (int t = 0; t < NKT; ++t) {
        short8v af[4], bfr[4];
        // ---- ks = 0 ----
        {
            const int c = (kg ^ l7s) * 8;
#pragma unroll
            for (int i = 0; i < 4; ++i)
                af[i] = *reinterpret_cast<const short8v*>(&lds[(wm * 64 + i * 16 + lr) * 64 + c]);
#pragma unroll
            for (int j = 0; j < 4; ++j)
                bfr[j] = *reinterpret_cast<const short8v*>(&lds[8192 + (wn * 64 + j * 16 + lr) * 64 + c]);
            asm volatile("s_waitcnt lgkmcnt(0)" ::: "memory");
            __builtin_amdgcn_sched_barrier(0);
            __builtin_amdgcn_s_setprio(1);
#pragma unroll
            for (int i = 0; i < 4; ++i)
#pragma unroll
                for (int j = 0; j < 4; ++j)
                    acc[i][j] = __builtin_amdgcn_mfma_f32_16x16x32_bf16(af[i], bfr[j], acc[i][j], 0, 0, 0);
            __builtin_amdgcn_s_setprio(0);
        }
        // ---- ks = 1 ----
        {
            const int c = ((4 + kg) ^ l7s) * 8;
#pragma unroll
            for (int i = 0; i < 4; ++i)
                af[i] = *reinterpret_cast<const short8v*>(&lds[(wm * 64 + i * 16 + lr) * 64 + c]);
#pragma unroll
            for (int j = 0; j < 4; ++j)
                bfr[j] = *reinterpret_cast<const short8v*>(&lds[8192 + (wn * 64 + j * 16 + lr) * 64 + c]);
            asm volatile("s_waitcnt lgkmcnt(0)" ::: "memory");
            __builtin_amdgcn_sched_barrier(0);
            __builtin_amdgcn_s_barrier();              // all waves done reading tile t
            if (t + 1 < NKT) STAGE(t + 1);             // overwrite buffer with next tile
            __builtin_amdgcn_s_setprio(1);
#pragma unroll
            for (int i = 0; i < 4; ++i)
#pragma unroll
                for (int j = 0; j < 4; ++j)
                    acc[i][j] = __builtin_amdgcn_mfma_f32_16x16x32_bf16(af[i], bfr[j], acc[i][j], 0, 0, 0);
            __builtin_amdgcn_s_setprio(0);
            if (t + 1 < NKT) {
                asm volatile("s_waitcnt vmcnt(0)" ::: "memory");
                __builtin_amdgcn_s_barrier();
            }
        }
    }
#undef STAGE

    // ---- epilogue: bias + exp + store + per-row exp-sum atomics
    int colb = lane & 15, rgrp = lane >> 4;
#pragma unroll
    for (int i = 0; i < 4; ++i) {
        float es0 = 0.f, es1 = 0.f, es2 = 0.f, es3 = 0.f;
        int gmb = m0 + wm * 64 + i * 16 + rgrp * 4;
#pragma unroll
        for (int j = 0; j < 4; ++j) {
            int gv = v0 + wn * 64 + j * 16 + colb;
            float bgj = bgen[gv];
            float v0f = acc[i][j][0] + bgj;
            float v1f = acc[i][j][1] + bgj;
            float v2f = acc[i][j][2] + bgj;
            float v3f = acc[i][j][3] + bgj;
            float e0 = __expf(v0f), e1 = __expf(v1f), e2 = __expf(v2f), e3 = __expf(v3f);
            if constexpr (EPI == 1) {
                ebuf[(size_t)(gmb + 0) * VV + gv] = f2bf(e0);
                ebuf[(size_t)(gmb + 1) * VV + gv] = f2bf(e1);
                ebuf[(size_t)(gmb + 2) * VV + gv] = f2bf(e2);
                ebuf[(size_t)(gmb + 3) * VV + gv] = f2bf(e3);
            } else {
                out[(size_t)(gmb + 0) * VV + gv] = v0f;
                out[(size_t)(gmb + 1) * VV + gv] = v1f;
                out[(size_t)(gmb + 2) * VV + gv] = v2f;
                out[(size_t)(gmb + 3) * VV + gv] = v3f;
            }
            es0 += e0; es1 += e1; es2 += e2; es3 += e3;
        }
        float es[4] = {es0, es1, es2, es3};
#pragma unroll
        for (int rr = 0; rr < 4; ++rr) {
            float e = es[rr];
            e += __shfl_xor(e, 1); e += __shfl_xor(e, 2);
            e += __shfl_xor(e, 4); e += __shfl_xor(e, 8);
            if (colb == 0) atomicAdd(&zg[gmb + rr], e);
        }
    }
}

// ---------------- fallback GEMM (f32 inputs, in-register cast, 128^2) ----------------
#define FBb 128
#define FLDK 40

__global__ __launch_bounds__(256) void k_gemm_f32(const float* __restrict__ A,
                                                  const float* __restrict__ Wg,
                                                  const float* __restrict__ bgen,
                                                  float* __restrict__ out,
                                                  float* __restrict__ zg) {
    __shared__ unsigned short As[FBb * FLDK];
    __shared__ unsigned short Bs[FBb * FLDK];
    int tid = threadIdx.x;
    int bid = blockIdx.x;
    int mt = bid & 7;
    int nt = bid >> 3;
    int m0 = mt * FBb, v0 = nt * FBb;
    int lane = tid & 63, wid = tid >> 6;
    int wr = (wid >> 1) * 64, wc = (wid & 1) * 64;
    int lr = lane & 15, lk = (lane >> 4) << 3;
    int r = tid >> 1, c0 = (tid & 1) << 4;

    f32x4 acc[4][4] = {};

    for (int k0 = 0; k0 < DD; k0 += 32) {
        {
            const float4* pa = reinterpret_cast<const float4*>(A + (size_t)(m0 + r) * DD + k0 + c0);
            float4 x0 = pa[0], x1 = pa[1], x2 = pa[2], x3 = pa[3];
            ushort8v u0, u1;
            u0[0] = f2bf(x0.x); u0[1] = f2bf(x0.y); u0[2] = f2bf(x0.z); u0[3] = f2bf(x0.w);
            u0[4] = f2bf(x1.x); u0[5] = f2bf(x1.y); u0[6] = f2bf(x1.z); u0[7] = f2bf(x1.w);
            u1[0] = f2bf(x2.x); u1[1] = f2bf(x2.y); u1[2] = f2bf(x2.z); u1[3] = f2bf(x2.w);
            u1[4] = f2bf(x3.x); u1[5] = f2bf(x3.y); u1[6] = f2bf(x3.z); u1[7] = f2bf(x3.w);
            *reinterpret_cast<ushort8v*>(&As[r * FLDK + c0]) = u0;
            *reinterpret_cast<ushort8v*>(&As[r * FLDK + c0 + 8]) = u1;

            const float4* pb = reinterpret_cast<const float4*>(Wg + (size_t)(v0 + r) * DD + k0 + c0);
            float4 y0 = pb[0], y1 = pb[1], y2 = pb[2], y3 = pb[3];
            ushort8v w0, w1;
            w0[0] = f2bf(y0.x); w0[1] = f2bf(y0.y); w0[2] = f2bf(y0.z); w0[3] = f2bf(y0.w);
            w0[4] = f2bf(y1.x); w0[5] = f2bf(y1.y); w0[6] = f2bf(y1.z); w0[7] = f2bf(y1.w);
            w1[0] = f2bf(y2.x); w1[1] = f2bf(y2.y); w1[2] = f2bf(y2.z); w1[3] = f2bf(y2.w);
            w1[4] = f2bf(y3.x); w1[5] = f2bf(y3.y); w1[6] = f2bf(y3.z); w1[7] = f2bf(y3.w);
            *reinterpret_cast<ushort8v*>(&Bs[r * FLDK + c0]) = w0;
            *reinterpret_cast<ushort8v*>(&Bs[r * FLDK + c0 + 8]) = w1;
        }
        __syncthreads();

        short8v af[4], bfr[4];
#pragma unroll
        for (int i = 0; i < 4; ++i)
            af[i] = *reinterpret_cast<const short8v*>(&As[(wr + i * 16 + lr) * FLDK + lk]);
#pragma unroll
        for (int j = 0; j < 4; ++j)
            bfr[j] = *reinterpret_cast<const short8v*>(&Bs[(wc + j * 16 + lr) * FLDK + lk]);
#pragma unroll
        for (int i = 0; i < 4; ++i)
#pragma unroll
            for (int j = 0; j < 4; ++j)
                acc[i][j] = __builtin_amdgcn_mfma_f32_16x16x32_bf16(af[i], bfr[j], acc[i][j], 0, 0, 0);
        __syncthreads();
    }

    int colb = lane & 15;
    int rgrp = lane >> 4;
#pragma unroll
    for (int i = 0; i < 4; ++i) {
        float es0 = 0.f, es1 = 0.f, es2 = 0.f, es3 = 0.f;
        int gmb = m0 + wr + i * 16 + rgrp * 4;
#pragma unroll
        for (int j = 0; j < 4; ++j) {
            int gv = v0 + wc + j * 16 + colb;
            float bgj = bgen[gv];
            float v0f = acc[i][j][0] + bgj;
            float v1f = acc[i][j][1] + bgj;
            float v2f = acc[i][j][2] + bgj;
            float v3f = acc[i][j][3] + bgj;
            out[(size_t)(gmb + 0) * VV + gv] = v0f;
            out[(size_t)(gmb + 1) * VV + gv] = v1f;
            out[(size_t)(gmb + 2) * VV + gv] = v2f;
            out[(size_t)(gmb + 3) * VV + gv] = v3f;
            es0 += __expf(v0f); es1 += __expf(v1f);
            es2 += __expf(v2f); es3 += __expf(v3f);
        }
        float es[4] = {es0, es1, es2, es3};
#pragma unroll
        for (int rr = 0; rr < 4; ++rr) {
            float e = es[rr];
            e += __shfl_xor(e, 1); e += __shfl_xor(e, 2);
            e += __shfl_xor(e, 4); e += __shfl_xor(e, 8);
            if (colb == 0) atomicAdd(&zg[gmb + rr], e);
        }
    }
}

// ---------------- final combine into d_out ----------------
// RD16=1: read bf16 exp(logit) from ebuf. RD16=0: read f32 logits from gen (in place).
template <int RD16>
__global__ __launch_bounds__(256) void k_final(float* __restrict__ gen,
                                               const unsigned short* __restrict__ ebuf,
                                               const int* __restrict__ pos_map,
                                               const float* __restrict__ e_vals,
                                               const float* __restrict__ prob,
                                               const float* __restrict__ zc,
                                               const float* __restrict__ c0,
                                               const float* __restrict__ zg) {
    int m = blockIdx.x;
    int b = m >> 7;
    int tid = threadIdx.x;
    float p = prob[m];
    float A1 = p / zg[m];
    float A2 = (1.0f - p) / zc[m];
    float cc = c0[m];
    const float* ev = e_vals + (size_t)m * SS;
    float4* row = reinterpret_cast<float4*>(gen + (size_t)m * VV);
    const int4* pm = reinterpret_cast<const int4*>(pos_map + b * VV);
    if constexpr (RD16 == 1) {
        const ushort8v* erow = reinterpret_cast<const ushort8v*>(ebuf + (size_t)m * VV);
        for (int i = tid; i < VV / 8; i += 256) {
            ushort8v ee = erow[i];
            int4 rp0 = pm[2 * i], rp1 = pm[2 * i + 1];
            float4 o0, o1;
            o0.x = __logf(A1 * bf2f(ee[0]) + A2 * ((rp0.x < SS) ? ev[rp0.x] : cc));
            o0.y = __logf(A1 * bf2f(ee[1]) + A2 * ((rp0.y < SS) ? ev[rp0.y] : cc));
            o0.z = __logf(A1 * bf2f(ee[2]) + A2 * ((rp0.z < SS) ? ev[rp0.z] : cc));
            o0.w = __logf(A1 * bf2f(ee[3]) + A2 * ((rp0.w < SS) ? ev[rp0.w] : cc));
            o1.x = __logf(A1 * bf2f(ee[4]) + A2 * ((rp1.x < SS) ? ev[rp1.x] : cc));
            o1.y = __logf(A1 * bf2f(ee[5]) + A2 * ((rp1.y < SS) ? ev[rp1.y] : cc));
            o1.z = __logf(A1 * bf2f(ee[6]) + A2 * ((rp1.z < SS) ? ev[rp1.z] : cc));
            o1.w = __logf(A1 * bf2f(ee[7]) + A2 * ((rp1.w < SS) ? ev[rp1.w] : cc));
            row[2 * i] = o0;
            row[2 * i + 1] = o1;
        }
    } else {
        for (int i = tid; i < VV / 4; i += 256) {
            float4 g = row[i];
            int4 rp = pm[i];
            float4 o;
            o.x = __logf(A1 * __expf(g.x) + A2 * ((rp.x < SS) ? ev[rp.x] : cc));
            o.y = __logf(A1 * __expf(g.y) + A2 * ((rp.y < SS) ? ev[rp.y] : cc));
            o.z = __logf(A1 * __expf(g.z) + A2 * ((rp.z < SS) ? ev[rp.z] : cc));
            o.w = __logf(A1 * __expf(g.w) + A2 * ((rp.w < SS) ? ev[rp.w] : cc));
            row[i] = o;
        }
    }
}

extern "C" void kernel_launch(void* const* d_in, const int* in_sizes, int n_in,
                              void* d_out, int out_size, void* d_ws, size_t ws_size,
                              hipStream_t stream) {
    const int* src = (const int*)d_in[0];
    const float* dec = (const float*)d_in[1];
    const float* dattn = (const float*)d_in[2];
    const float* mem = (const float*)d_in[3];
    const float* wgen = (const float*)d_in[4];
    const float* bgen = (const float*)d_in[5];
    const float* wprob = (const float*)d_in[6];
    const float* bprob = (const float*)d_in[7];
    float* out = (float*)d_out;
    char* ws = (char*)d_ws;

    // ws layout
    int* pos_map = (int*)(ws + 0);                       // 1,024,000 B (pad 1 MB)
    float* e_vals = (float*)(ws + 1048576);              // 2 MB
    float* mw   = (float*)(ws + 3145728);                // 16 KB
    float* dw   = (float*)(ws + 3145728 + 16384);
    float* prob = (float*)(ws + 3145728 + 20480);
    float* zc   = (float*)(ws + 3145728 + 24576);
    float* c0   = (float*)(ws + 3145728 + 28672);
    float* zg   = (float*)(ws + 3145728 + 32768);
    unsigned short* Wbf = (unsigned short*)(ws + 3211264);              // 65,536,000 B
    unsigned short* Abf = (unsigned short*)(ws + 3211264 + 65536000);   // 2 MB
    unsigned short* Ebf = (unsigned short*)(ws + 3211264 + 65536000 + 2097152);  // 65,536,000 B
    const size_t NEEDED  = 3211264ull + 65536000ull + 2097152ull;
    const size_t NEEDED2 = NEEDED + 65536000ull;

    k_pm_init<<<(BB * VV + 255) / 256, 256, 0, stream>>>(pos_map, zg);
    k_pm_build<<<BB, SS, 0, stream>>>(src, pos_map);
    k_vecdots<<<(BB * SS + MM) / 4, 256, 0, stream>>>(mem, dec, wprob, mw, dw);
    k_row<<<MM, 256, 0, stream>>>(dattn, src, pos_map, mw, dw, bprob, e_vals, prob, zc, c0);

    if (ws_size >= NEEDED) {
        k_cast<<<2048, 256, 0, stream>>>(wgen, Wbf, VV * DD / 8);
        k_cast<<<512, 256, 0, stream>>>(dec, Abf, MM * DD / 8);
        if (ws_size >= NEEDED2) {
            k_gemm_bf<1><<<(MM / 128) * (VV / 256), 512, 0, stream>>>(Abf, Wbf, bgen, out, Ebf, zg);
            k_final<1><<<MM, 256, 0, stream>>>(out, Ebf, pos_map, e_vals, prob, zc, c0, zg);
        } else {
            k_gemm_bf<0><<<(MM / 128) * (VV / 256), 512, 0, stream>>>(Abf, Wbf, bgen, out, Ebf, zg);
            k_final<0><<<MM, 256, 0, stream>>>(out, Ebf, pos_map, e_vals, prob, zc, c0, zg);
        }
    } else {
        k_gemm_f32<<<(MM / FBb) * (VV / FBb), 256, 0, stream>>>(dec, wgen, bgen, out, zg);
        k_final<0><<<MM, 256, 0, stream>>>(out, Ebf, pos_map, e_vals, prob, zc, c0, zg);
    }
}

// Round 6
// 221.566 us; speedup vs baseline: 1.4060x; 1.0386x over previous
//
#include <hip/hip_runtime.h>
#include <hip/hip_bf16.h>
#include <cstddef>
#include <cstdint>

// Problem constants
#define BB 8
#define HH 16
#define TT 128
#define SS 512
#define DD 1024
#define VV 32000
#define MM (BB * TT)   // 1024 output rows

typedef float f32x4 __attribute__((ext_vector_type(4)));
typedef short short8v __attribute__((ext_vector_type(8)));
typedef unsigned short ushort8v __attribute__((ext_vector_type(8)));

__device__ __forceinline__ unsigned short f2bf(float x) {
    __hip_bfloat16 h = __float2bfloat16(x);
    return __builtin_bit_cast(unsigned short, h);
}
__device__ __forceinline__ float bf2f(unsigned short u) {
    unsigned int x = ((unsigned int)u) << 16;
    return __builtin_bit_cast(float, x);
}

__device__ __forceinline__ float wave_sum(float v) {
#pragma unroll
    for (int o = 1; o < 64; o <<= 1) v += __shfl_xor(v, o);
    return v;
}
__device__ __forceinline__ float wave_max(float v) {
#pragma unroll
    for (int o = 1; o < 64; o <<= 1) v = fmaxf(v, __shfl_xor(v, o));
    return v;
}
__device__ __forceinline__ float block_sum(float v, float* red, int tid) {
    v = wave_sum(v);
    __syncthreads();
    if ((tid & 63) == 0) red[tid >> 6] = v;
    __syncthreads();
    return red[0] + red[1] + red[2] + red[3];
}
__device__ __forceinline__ float block_max(float v, float* red, int tid) {
    v = wave_max(v);
    __syncthreads();
    if ((tid & 63) == 0) red[tid >> 6] = v;
    __syncthreads();
    return fmaxf(fmaxf(red[0], red[1]), fmaxf(red[2], red[3]));
}

// ---------------- pos_map build + zg zero ----------------
__global__ void k_pm_init(int* pos_map, float* zg) {
    int i = blockIdx.x * 256 + threadIdx.x;
    if (i < BB * VV) pos_map[i] = 0x7fffffff;
    if (i < MM) zg[i] = 0.0f;
}

__global__ void k_pm_build(const int* __restrict__ src, int* pos_map) {
    int b = blockIdx.x, s = threadIdx.x;  // 8 x 512
    int tok = src[b * SS + s];
    atomicMin(&pos_map[b * VV + tok], s);
}

// ---------------- f32 -> bf16 cast (8 elems/thread, grid-stride) ----------------
__global__ __launch_bounds__(256) void k_cast(const float* __restrict__ in,
                                              unsigned short* __restrict__ outp, int n8) {
    int stride = gridDim.x * 256;
    for (int i = blockIdx.x * 256 + threadIdx.x; i < n8; i += stride) {
        const float4* p = reinterpret_cast<const float4*>(in + (size_t)i * 8);
        float4 a = p[0], b = p[1];
        ushort8v u;
        u[0] = f2bf(a.x); u[1] = f2bf(a.y); u[2] = f2bf(a.z); u[3] = f2bf(a.w);
        u[4] = f2bf(b.x); u[5] = f2bf(b.y); u[6] = f2bf(b.z); u[7] = f2bf(b.w);
        *reinterpret_cast<ushort8v*>(outp + (size_t)i * 8) = u;
    }
}

// ---------------- mw / dw dot products ----------------
__global__ __launch_bounds__(256) void k_vecdots(const float* __restrict__ memory,
                                                 const float* __restrict__ dec,
                                                 const float* __restrict__ wprob,
                                                 float* mw, float* dw) {
    int row = blockIdx.x * 4 + (threadIdx.x >> 6);
    int lane = threadIdx.x & 63;
    const float4* srcv;
    const float4* wv;
    if (row < BB * SS) {
        srcv = reinterpret_cast<const float4*>(memory + (size_t)row * DD);
        wv = reinterpret_cast<const float4*>(wprob);
    } else {
        srcv = reinterpret_cast<const float4*>(dec + (size_t)(row - BB * SS) * DD);
        wv = reinterpret_cast<const float4*>(wprob + DD);
    }
    float sum = 0.f;
#pragma unroll
    for (int k = 0; k < 4; ++k) {
        int idx = lane + 64 * k;
        float4 a = srcv[idx];
        float4 w = wv[idx];
        sum += a.x * w.x + a.y * w.y + a.z * w.z + a.w * w.w;
    }
    sum = wave_sum(sum);
    if (lane == 0) {
        if (row < BB * SS) mw[row] = sum;
        else dw[row - BB * SS] = sum;
    }
}

// ---------------- per-(b,t) row: attn mean, scatter, prob, copy-Z ----------------
__global__ __launch_bounds__(256) void k_row(const float* __restrict__ dattn,
                                             const int* __restrict__ src,
                                             const int* __restrict__ pos_map,
                                             const float* __restrict__ mw,
                                             const float* __restrict__ dw,
                                             const float* __restrict__ bprob,
                                             float* __restrict__ e_vals,
                                             float* __restrict__ prob,
                                             float* __restrict__ zc,
                                             float* __restrict__ c0) {
    int bt = blockIdx.x;
    int b = bt >> 7;
    int t = bt & 127;
    int tid = threadIdx.x;
    __shared__ float a_row[SS];
    __shared__ float vals[SS];
    __shared__ float red[4];

    for (int s = tid; s < SS; s += 256) {
        const float* base = dattn + ((size_t)b * HH * TT + t) * SS + s;
        float sum = 0.f;
#pragma unroll
        for (int h = 0; h < HH; ++h) sum += base[(size_t)h * TT * SS];
        a_row[s] = sum * 0.0625f;
        vals[s] = 0.f;
    }
    __syncthreads();
    for (int s = tid; s < SS; s += 256) {
        int rep = pos_map[b * VV + src[b * SS + s]];
        atomicAdd(&vals[rep], a_row[s]);
    }
    __syncthreads();
    float psum = 0.f;
    for (int s = tid; s < SS; s += 256) psum += a_row[s] * mw[b * SS + s];
    psum = block_sum(psum, red, tid);
    float z = psum + dw[bt] + bprob[0];
    float p = 1.0f / (1.0f + __expf(-z));
    float mxv = -3.4e38f;
    for (int s = tid; s < SS; s += 256) {
        int rep = pos_map[b * VV + src[b * SS + s]];
        if (rep == s) mxv = fmaxf(mxv, vals[s]);
    }
    mxv = block_max(mxv, red, tid);
    float m_c = fmaxf(0.0f, mxv);
    float sexp = 0.f, cnt = 0.f;
    for (int s = tid; s < SS; s += 256) {
        int rep = pos_map[b * VV + src[b * SS + s]];
        float e = 0.0f;
        if (rep == s) {
            e = __expf(vals[s] - m_c);
            sexp += e;
            cnt += 1.0f;
        }
        e_vals[(size_t)bt * SS + s] = e;
    }
    sexp = block_sum(sexp, red, tid);
    cnt = block_sum(cnt, red, tid);
    if (tid == 0) {
        prob[bt] = p;
        zc[bt] = ((float)VV - cnt) * __expf(-m_c) + sexp;
        c0[bt] = __expf(-m_c);
    }
}

// =====================================================================
// 128x256 bf16 MFMA GEMM, 8 waves (64x64 each), BK=32, TRIPLE buffer,
// 2-deep prefetch with counted vmcnt(3). 72 KiB LDS -> 2 blocks/CU,
// 16 waves/CU. BK=32 row-major is bank-uniform (no swizzle needed).
// Grid 1000 = 8 XCD x 125 bijective swizzle.
// EPI=1: store bf16 exp(logit) to ebuf; EPI=0: f32 logits to out.
// =====================================================================
#define NKT 32          // K tiles = 1024/32
#define BUFE 12288      // elems per buffer: A 128*32=4096 + B 256*32=8192

#define AS1 __attribute__((address_space(1)))
#define AS3 __attribute__((address_space(3)))

template <int EPI>
__global__ __launch_bounds__(512, 4) void k_gemm_bf(const unsigned short* __restrict__ Abf,
                                                    const unsigned short* __restrict__ Wbf,
                                                    const float* __restrict__ bgen,
                                                    float* __restrict__ out,
                                                    unsigned short* __restrict__ ebuf,
                                                    float* __restrict__ zg) {
    __shared__ unsigned short lds[3 * BUFE];   // 72 KiB

    int tid = threadIdx.x;
    int p = blockIdx.x;
    // bijective XCD swizzle: 1000 = 8 * 125
    int wg = (p & 7) * 125 + (p >> 3);
    int mt = wg & 7, nt = wg >> 3;     // consecutive wg share nt -> W L2 reuse
    int m0 = mt * 128, v0 = nt * 256;

    int lane = tid & 63, w = tid >> 6;
    int wm = w & 1, wn = w >> 1;       // wave owns 64(M) x 64(N)

    // staging: thread -> (row = tid>>2, 16B chunk = tid&3); linear LDS dest
    int srow = tid >> 2;               // 0..127
    int scol = (tid & 3) << 3;         // bf16 col offset 0/8/16/24
    const unsigned short* gA = Abf + (size_t)(m0 + srow) * DD + scol;
    const unsigned short* gB = Wbf + (size_t)(v0 + srow) * DD + scol;

    // per tile: 1 A-load + 2 B-loads per thread (vmcnt granularity = 3)
#define STAGE(T, BI) do {                                                              \
    size_t ko_ = (size_t)(T) * 32;                                                     \
    __builtin_amdgcn_global_load_lds(                                                  \
        (const AS1 void*)(gA + ko_),                                                   \
        (AS3 void*)(lds + (BI) * BUFE + tid * 8), 16, 0, 0);                           \
    __builtin_amdgcn_global_load_lds(                                                  \
        (const AS1 void*)(gB + ko_),                                                   \
        (AS3 void*)(lds + (BI) * BUFE + 4096 + tid * 8), 16, 0, 0);                    \
    __builtin_amdgcn_global_load_lds(                                                  \
        (const AS1 void*)(gB + (size_t)128 * DD + ko_),                                \
        (AS3 void*)(lds + (BI) * BUFE + 8192 + tid * 8), 16, 0, 0);                    \
} while (0)

    int lr = lane & 15, kg8 = (lane >> 4) << 3;
    const unsigned short* arow = lds + (wm * 64 + lr) * 32 + kg8;
    const unsigned short* brow = lds + 4096 + (wn * 64 + lr) * 32 + kg8;

    f32x4 acc[4][4] = {};

    // one compute iteration on buffer BI, optional stage of tile T+2
#define ITER(T, BI, DO_STAGE, VM)  do {                                                \
    __builtin_amdgcn_s_barrier();                                                      \
    short8v af[4], bfr[4];                                                             \
    _Pragma("unroll")                                                                  \
    for (int i = 0; i < 4; ++i)                                                        \
        af[i] = *reinterpret_cast<const short8v*>(arow + (BI) * BUFE + i * (16 * 32)); \
    _Pragma("unroll")                                                                  \
    for (int j = 0; j < 4; ++j)                                                        \
        bfr[j] = *reinterpret_cast<const short8v*>(brow + (BI) * BUFE + j * (16 * 32));\
    if (DO_STAGE) STAGE((T) + 2, ((BI) + 2) % 3);                                      \
    asm volatile("s_waitcnt lgkmcnt(0)" ::: "memory");                                 \
    __builtin_amdgcn_sched_barrier(0);                                                 \
    __builtin_amdgcn_s_setprio(1);                                                     \
    _Pragma("unroll")                                                                  \
    for (int i = 0; i < 4; ++i)                                                        \
        _Pragma("unroll")                                                              \
        for (int j = 0; j < 4; ++j)                                                    \
            acc[i][j] = __builtin_amdgcn_mfma_f32_16x16x32_bf16(af[i], bfr[j], acc[i][j], 0, 0, 0); \
    __builtin_amdgcn_s_setprio(0);                                                     \
    if ((VM) == 3) asm volatile("s_waitcnt vmcnt(3)" ::: "memory");                    \
    else if ((VM) == 0) asm volatile("s_waitcnt vmcnt(0)" ::: "memory");               \
} while (0)

    // prologue: stage tiles 0,1; wait tile 0 (3 newest = tile 1 still in flight)
    STAGE(0, 0);
    STAGE(1, 1);
    asm volatile("s_waitcnt vmcnt(3)" ::: "memory");

    // main: t = 0..29 (stages t+2), static buffer indices via 3x unroll
    for (int t = 0; t < NKT - 2; t += 3) {
        ITER(t + 0, 0, true, 3);
        ITER(t + 1, 1, true, 3);
        ITER(t + 2, 2, true, 3);
    }
    // tails: t=30 (buf 0, wait last tile), t=31 (buf 1)
    ITER(30, 0, false, 0);
    ITER(31, 1, false, -1);
#undef ITER
#undef STAGE

    // ---- epilogue: bias + exp + store + per-row exp-sum atomics
    int colb = lane & 15, rgrp = lane >> 4;
#pragma unroll
    for (int i = 0; i < 4; ++i) {
        float es0 = 0.f, es1 = 0.f, es2 = 0.f, es3 = 0.f;
        int gmb = m0 + wm * 64 + i * 16 + rgrp * 4;
#pragma unroll
        for (int j = 0; j < 4; ++j) {
            int gv = v0 + wn * 64 + j * 16 + colb;
            float bgj = bgen[gv];
            float v0f = acc[i][j][0] + bgj;
            float v1f = acc[i][j][1] + bgj;
            float v2f = acc[i][j][2] + bgj;
            float v3f = acc[i][j][3] + bgj;
            float e0 = __expf(v0f), e1 = __expf(v1f), e2 = __expf(v2f), e3 = __expf(v3f);
            if constexpr (EPI == 1) {
                ebuf[(size_t)(gmb + 0) * VV + gv] = f2bf(e0);
                ebuf[(size_t)(gmb + 1) * VV + gv] = f2bf(e1);
                ebuf[(size_t)(gmb + 2) * VV + gv] = f2bf(e2);
                ebuf[(size_t)(gmb + 3) * VV + gv] = f2bf(e3);
            } else {
                out[(size_t)(gmb + 0) * VV + gv] = v0f;
                out[(size_t)(gmb + 1) * VV + gv] = v1f;
                out[(size_t)(gmb + 2) * VV + gv] = v2f;
                out[(size_t)(gmb + 3) * VV + gv] = v3f;
            }
            es0 += e0; es1 += e1; es2 += e2; es3 += e3;
        }
        float es[4] = {es0, es1, es2, es3};
#pragma unroll
        for (int rr = 0; rr < 4; ++rr) {
            float e = es[rr];
            e += __shfl_xor(e, 1); e += __shfl_xor(e, 2);
            e += __shfl_xor(e, 4); e += __shfl_xor(e, 8);
            if (colb == 0) atomicAdd(&zg[gmb + rr], e);
        }
    }
}

// ---------------- fallback GEMM (f32 inputs, in-register cast, 128^2) ----------------
#define FBb 128
#define FLDK 40

__global__ __launch_bounds__(256) void k_gemm_f32(const float* __restrict__ A,
                                                  const float* __restrict__ Wg,
                                                  const float* __restrict__ bgen,
                                                  float* __restrict__ out,
                                                  float* __restrict__ zg) {
    __shared__ unsigned short As[FBb * FLDK];
    __shared__ unsigned short Bs[FBb * FLDK];
    int tid = threadIdx.x;
    int bid = blockIdx.x;
    int mt = bid & 7;
    int nt = bid >> 3;
    int m0 = mt * FBb, v0 = nt * FBb;
    int lane = tid & 63, wid = tid >> 6;
    int wr = (wid >> 1) * 64, wc = (wid & 1) * 64;
    int lr = lane & 15, lk = (lane >> 4) << 3;
    int r = tid >> 1, c0 = (tid & 1) << 4;

    f32x4 acc[4][4] = {};

    for (int k0 = 0; k0 < DD; k0 += 32) {
        {
            const float4* pa = reinterpret_cast<const float4*>(A + (size_t)(m0 + r) * DD + k0 + c0);
            float4 x0 = pa[0], x1 = pa[1], x2 = pa[2], x3 = pa[3];
            ushort8v u0, u1;
            u0[0] = f2bf(x0.x); u0[1] = f2bf(x0.y); u0[2] = f2bf(x0.z); u0[3] = f2bf(x0.w);
            u0[4] = f2bf(x1.x); u0[5] = f2bf(x1.y); u0[6] = f2bf(x1.z); u0[7] = f2bf(x1.w);
            u1[0] = f2bf(x2.x); u1[1] = f2bf(x2.y); u1[2] = f2bf(x2.z); u1[3] = f2bf(x2.w);
            u1[4] = f2bf(x3.x); u1[5] = f2bf(x3.y); u1[6] = f2bf(x3.z); u1[7] = f2bf(x3.w);
            *reinterpret_cast<ushort8v*>(&As[r * FLDK + c0]) = u0;
            *reinterpret_cast<ushort8v*>(&As[r * FLDK + c0 + 8]) = u1;

            const float4* pb = reinterpret_cast<const float4*>(Wg + (size_t)(v0 + r) * DD + k0 + c0);
            float4 y0 = pb[0], y1 = pb[1], y2 = pb[2], y3 = pb[3];
            ushort8v w0, w1;
            w0[0] = f2bf(y0.x); w0[1] = f2bf(y0.y); w0[2] = f2bf(y0.z); w0[3] = f2bf(y0.w);
            w0[4] = f2bf(y1.x); w0[5] = f2bf(y1.y); w0[6] = f2bf(y1.z); w0[7] = f2bf(y1.w);
            w1[0] = f2bf(y2.x); w1[1] = f2bf(y2.y); w1[2] = f2bf(y2.z); w1[3] = f2bf(y2.w);
            w1[4] = f2bf(y3.x); w1[5] = f2bf(y3.y); w1[6] = f2bf(y3.z); w1[7] = f2bf(y3.w);
            *reinterpret_cast<ushort8v*>(&Bs[r * FLDK + c0]) = w0;
            *reinterpret_cast<ushort8v*>(&Bs[r * FLDK + c0 + 8]) = w1;
        }
        __syncthreads();

        short8v af[4], bfr[4];
#pragma unroll
        for (int i = 0; i < 4; ++i)
            af[i] = *reinterpret_cast<const short8v*>(&As[(wr + i * 16 + lr) * FLDK + lk]);
#pragma unroll
        for (int j = 0; j < 4; ++j)
            bfr[j] = *reinterpret_cast<const short8v*>(&Bs[(wc + j * 16 + lr) * FLDK + lk]);
#pragma unroll
        for (int i = 0; i < 4; ++i)
#pragma unroll
            for (int j = 0; j < 4; ++j)
                acc[i][j] = __builtin_amdgcn_mfma_f32_16x16x32_bf16(af[i], bfr[j], acc[i][j], 0, 0, 0);
        __syncthreads();
    }

    int colb = lane & 15;
    int rgrp = lane >> 4;
#pragma unroll
    for (int i = 0; i < 4; ++i) {
        float es0 = 0.f, es1 = 0.f, es2 = 0.f, es3 = 0.f;
        int gmb = m0 + wr + i * 16 + rgrp * 4;
#pragma unroll
        for (int j = 0; j < 4; ++j) {
            int gv = v0 + wc + j * 16 + colb;
            float bgj = bgen[gv];
            float v0f = acc[i][j][0] + bgj;
            float v1f = acc[i][j][1] + bgj;
            float v2f = acc[i][j][2] + bgj;
            float v3f = acc[i][j][3] + bgj;
            out[(size_t)(gmb + 0) * VV + gv] = v0f;
            out[(size_t)(gmb + 1) * VV + gv] = v1f;
            out[(size_t)(gmb + 2) * VV + gv] = v2f;
            out[(size_t)(gmb + 3) * VV + gv] = v3f;
            es0 += __expf(v0f); es1 += __expf(v1f);
            es2 += __expf(v2f); es3 += __expf(v3f);
        }
        float es[4] = {es0, es1, es2, es3};
#pragma unroll
        for (int rr = 0; rr < 4; ++rr) {
            float e = es[rr];
            e += __shfl_xor(e, 1); e += __shfl_xor(e, 2);
            e += __shfl_xor(e, 4); e += __shfl_xor(e, 8);
            if (colb == 0) atomicAdd(&zg[gmb + rr], e);
        }
    }
}

// ---------------- final combine into d_out ----------------
// RD16=1: read bf16 exp(logit) from ebuf. RD16=0: read f32 logits from gen (in place).
template <int RD16>
__global__ __launch_bounds__(256) void k_final(float* __restrict__ gen,
                                               const unsigned short* __restrict__ ebuf,
                                               const int* __restrict__ pos_map,
                                               const float* __restrict__ e_vals,
                                               const float* __restrict__ prob,
                                               const float* __restrict__ zc,
                                               const float* __restrict__ c0,
                                               const float* __restrict__ zg) {
    int m = blockIdx.x;
    int b = m >> 7;
    int tid = threadIdx.x;
    float p = prob[m];
    float A1 = p / zg[m];
    float A2 = (1.0f - p) / zc[m];
    float cc = c0[m];
    const float* ev = e_vals + (size_t)m * SS;
    float4* row = reinterpret_cast<float4*>(gen + (size_t)m * VV);
    const int4* pm = reinterpret_cast<const int4*>(pos_map + b * VV);
    if constexpr (RD16 == 1) {
        const ushort8v* erow = reinterpret_cast<const ushort8v*>(ebuf + (size_t)m * VV);
        for (int i = tid; i < VV / 8; i += 256) {
            ushort8v ee = erow[i];
            int4 rp0 = pm[2 * i], rp1 = pm[2 * i + 1];
            float4 o0, o1;
            o0.x = __logf(A1 * bf2f(ee[0]) + A2 * ((rp0.x < SS) ? ev[rp0.x] : cc));
            o0.y = __logf(A1 * bf2f(ee[1]) + A2 * ((rp0.y < SS) ? ev[rp0.y] : cc));
            o0.z = __logf(A1 * bf2f(ee[2]) + A2 * ((rp0.z < SS) ? ev[rp0.z] : cc));
            o0.w = __logf(A1 * bf2f(ee[3]) + A2 * ((rp0.w < SS) ? ev[rp0.w] : cc));
            o1.x = __logf(A1 * bf2f(ee[4]) + A2 * ((rp1.x < SS) ? ev[rp1.x] : cc));
            o1.y = __logf(A1 * bf2f(ee[5]) + A2 * ((rp1.y < SS) ? ev[rp1.y] : cc));
            o1.z = __logf(A1 * bf2f(ee[6]) + A2 * ((rp1.z < SS) ? ev[rp1.z] : cc));
            o1.w = __logf(A1 * bf2f(ee[7]) + A2 * ((rp1.w < SS) ? ev[rp1.w] : cc));
            row[2 * i] = o0;
            row[2 * i + 1] = o1;
        }
    } else {
        for (int i = tid; i < VV / 4; i += 256) {
            float4 g = row[i];
            int4 rp = pm[i];
            float4 o;
            o.x = __logf(A1 * __expf(g.x) + A2 * ((rp.x < SS) ? ev[rp.x] : cc));
            o.y = __logf(A1 * __expf(g.y) + A2 * ((rp.y < SS) ? ev[rp.y] : cc));
            o.z = __logf(A1 * __expf(g.z) + A2 * ((rp.z < SS) ? ev[rp.z] : cc));
            o.w = __logf(A1 * __expf(g.w) + A2 * ((rp.w < SS) ? ev[rp.w] : cc));
            row[i] = o;
        }
    }
}

extern "C" void kernel_launch(void* const* d_in, const int* in_sizes, int n_in,
                              void* d_out, int out_size, void* d_ws, size_t ws_size,
                              hipStream_t stream) {
    const int* src = (const int*)d_in[0];
    const float* dec = (const float*)d_in[1];
    const float* dattn = (const float*)d_in[2];
    const float* mem = (const float*)d_in[3];
    const float* wgen = (const float*)d_in[4];
    const float* bgen = (const float*)d_in[5];
    const float* wprob = (const float*)d_in[6];
    const float* bprob = (const float*)d_in[7];
    float* out = (float*)d_out;
    char* ws = (char*)d_ws;

    // ws layout
    int* pos_map = (int*)(ws + 0);                       // 1,024,000 B (pad 1 MB)
    float* e_vals = (float*)(ws + 1048576);              // 2 MB
    float* mw   = (float*)(ws + 3145728);                // 16 KB
    float* dw   = (float*)(ws + 3145728 + 16384);
    float* prob = (float*)(ws + 3145728 + 20480);
    float* zc   = (float*)(ws + 3145728 + 24576);
    float* c0   = (float*)(ws + 3145728 + 28672);
    float* zg   = (float*)(ws + 3145728 + 32768);
    unsigned short* Wbf = (unsigned short*)(ws + 3211264);              // 65,536,000 B
    unsigned short* Abf = (unsigned short*)(ws + 3211264 + 65536000);   // 2 MB
    unsigned short* Ebf = (unsigned short*)(ws + 3211264 + 65536000 + 2097152);  // 65,536,000 B
    const size_t NEEDED  = 3211264ull + 65536000ull + 2097152ull;
    const size_t NEEDED2 = NEEDED + 65536000ull;

    k_pm_init<<<(BB * VV + 255) / 256, 256, 0, stream>>>(pos_map, zg);
    k_pm_build<<<BB, SS, 0, stream>>>(src, pos_map);
    k_vecdots<<<(BB * SS + MM) / 4, 256, 0, stream>>>(mem, dec, wprob, mw, dw);
    k_row<<<MM, 256, 0, stream>>>(dattn, src, pos_map, mw, dw, bprob, e_vals, prob, zc, c0);

    if (ws_size >= NEEDED) {
        k_cast<<<2048, 256, 0, stream>>>(wgen, Wbf, VV * DD / 8);
        k_cast<<<512, 256, 0, stream>>>(dec, Abf, MM * DD / 8);
        if (ws_size >= NEEDED2) {
            k_gemm_bf<1><<<(MM / 128) * (VV / 256), 512, 0, stream>>>(Abf, Wbf, bgen, out, Ebf, zg);
            k_final<1><<<MM, 256, 0, stream>>>(out, Ebf, pos_map, e_vals, prob, zc, c0, zg);
        } else {
            k_gemm_bf<0><<<(MM / 128) * (VV / 256), 512, 0, stream>>>(Abf, Wbf, bgen, out, Ebf, zg);
            k_final<0><<<MM, 256, 0, stream>>>(out, Ebf, pos_map, e_vals, prob, zc, c0, zg);
        }
    } else {
        k_gemm_f32<<<(MM / FBb) * (VV / FBb), 256, 0, stream>>>(dec, wgen, bgen, out, zg);
        k_final<0><<<MM, 256, 0, stream>>>(out, Ebf, pos_map, e_vals, prob, zc, c0, zg);
    }
}